// Round 1
// baseline (6159.708 us; speedup 1.0000x reference)
//
#include <hip/hip_runtime.h>
#include <math.h>

#define N_NODES 50000
#define N_EDGES 800000
#define ETOT    (N_EDGES + N_NODES)
#define FDIM    256
#define HDIM    256
#define NGRAPH  64
#define C_OUT   10
#define BN_EPS  1e-5f
#define ATT_SLOPE 0.2f
#define ACT_SLOPE 0.01f

__device__ __forceinline__ float leaky(float x, float s) { return x >= 0.f ? x : s * x; }

__device__ __forceinline__ void atomicMaxF(float* addr, float v) {
    if (v >= 0.f) atomicMax((int*)addr, __float_as_int(v));
    else          atomicMin((unsigned int*)addr, __float_as_uint(v));
}

__device__ __forceinline__ void edge_sd(const int* __restrict__ ei, int e, int& s, int& d) {
    if (e < N_EDGES) { s = ei[e]; d = ei[N_EDGES + e]; }
    else             { s = e - N_EDGES; d = s; }
}

// ---------------- GEMM: C[M,256] = A[M,256] @ B[256,256], fp32 ----------------
__global__ __launch_bounds__(256) void gemm_f32(const float* __restrict__ A,
                                                const float* __restrict__ Bw,
                                                float* __restrict__ Cc, int M) {
    __shared__ float As[64][68];
    __shared__ float Bs[64][68];
    const int tid = threadIdx.x;
    const int tx = tid & 15, ty = tid >> 4;
    const int row0 = blockIdx.x * 64, col0 = blockIdx.y * 64;
    float acc[4][4] = {};
    for (int kk = 0; kk < FDIM; kk += 64) {
        const int lr = tid >> 4;          // 0..15
        const int lc4 = (tid & 15) * 4;   // 0..60
        #pragma unroll
        for (int q = 0; q < 4; ++q) {
            int rr = lr + q * 16;
            int grow = row0 + rr;
            float4 av;
            if (grow < M) av = *(const float4*)&A[(size_t)grow * FDIM + kk + lc4];
            else          av = make_float4(0.f, 0.f, 0.f, 0.f);
            *(float4*)&As[rr][lc4] = av;
            float4 bv = *(const float4*)&Bw[(size_t)(kk + rr) * HDIM + col0 + lc4];
            *(float4*)&Bs[rr][lc4] = bv;
        }
        __syncthreads();
        #pragma unroll 8
        for (int k = 0; k < 64; ++k) {
            float a0 = As[ty * 4 + 0][k];
            float a1 = As[ty * 4 + 1][k];
            float a2 = As[ty * 4 + 2][k];
            float a3 = As[ty * 4 + 3][k];
            float4 b4 = *(float4*)&Bs[k][tx * 4];
            acc[0][0] += a0 * b4.x; acc[0][1] += a0 * b4.y; acc[0][2] += a0 * b4.z; acc[0][3] += a0 * b4.w;
            acc[1][0] += a1 * b4.x; acc[1][1] += a1 * b4.y; acc[1][2] += a1 * b4.z; acc[1][3] += a1 * b4.w;
            acc[2][0] += a2 * b4.x; acc[2][1] += a2 * b4.y; acc[2][2] += a2 * b4.z; acc[2][3] += a2 * b4.w;
            acc[3][0] += a3 * b4.x; acc[3][1] += a3 * b4.y; acc[3][2] += a3 * b4.z; acc[3][3] += a3 * b4.w;
        }
        __syncthreads();
    }
    #pragma unroll
    for (int i = 0; i < 4; ++i) {
        int grow = row0 + ty * 4 + i;
        if (grow < M) {
            float4 v = make_float4(acc[i][0], acc[i][1], acc[i][2], acc[i][3]);
            *(float4*)&Cc[(size_t)grow * HDIM + col0 + tx * 4] = v;
        }
    }
}

// ------------- per-row dual dot: e_src[i]=h[i].a_src, e_dst[i]=h[i].a_dst -------------
__global__ __launch_bounds__(256) void row_dots(const float* __restrict__ h,
                                                const float* __restrict__ av_s,
                                                const float* __restrict__ av_d,
                                                float* __restrict__ es, float* __restrict__ ed) {
    int row = blockIdx.x * 4 + (threadIdx.x >> 6);
    int lane = threadIdx.x & 63;
    if (row >= N_NODES) return;
    float4 hv = *(const float4*)&h[(size_t)row * HDIM + lane * 4];
    float4 s4 = *(const float4*)&av_s[lane * 4];
    float4 d4 = *(const float4*)&av_d[lane * 4];
    float vs = hv.x * s4.x + hv.y * s4.y + hv.z * s4.z + hv.w * s4.w;
    float vd = hv.x * d4.x + hv.y * d4.y + hv.z * d4.z + hv.w * d4.w;
    #pragma unroll
    for (int off = 32; off; off >>= 1) {
        vs += __shfl_down(vs, off);
        vd += __shfl_down(vd, off);
    }
    if (lane == 0) { es[row] = vs; ed[row] = vd; }
}

__global__ __launch_bounds__(256) void node_init(float* __restrict__ m, float* __restrict__ s) {
    int i = blockIdx.x * 256 + threadIdx.x;
    if (i < N_NODES) { m[i] = -INFINITY; s[i] = 0.f; }
}

__global__ __launch_bounds__(256) void edge_max_k(const int* __restrict__ ei,
                                                  const float* __restrict__ es,
                                                  const float* __restrict__ ed,
                                                  float* __restrict__ m) {
    int e = blockIdx.x * 256 + threadIdx.x;
    if (e >= ETOT) return;
    int s, d; edge_sd(ei, e, s, d);
    float v = leaky(es[s] + ed[d], ATT_SLOPE);
    atomicMaxF(&m[d], v);
}

__global__ __launch_bounds__(256) void edge_sum_k(const int* __restrict__ ei,
                                                  const float* __restrict__ es,
                                                  const float* __restrict__ ed,
                                                  const float* __restrict__ m,
                                                  float* __restrict__ ssum) {
    int e = blockIdx.x * 256 + threadIdx.x;
    if (e >= ETOT) return;
    int s, d; edge_sd(ei, e, s, d);
    float v = leaky(es[s] + ed[d], ATT_SLOPE);
    atomicAdd(&ssum[d], expf(v - m[d]));
}

// one wave per edge; lane handles 4 features
__global__ __launch_bounds__(256) void edge_agg_k(const int* __restrict__ ei,
                                                  const float* __restrict__ es,
                                                  const float* __restrict__ ed,
                                                  const float* __restrict__ m,
                                                  const float* __restrict__ ssum,
                                                  const float* __restrict__ h,
                                                  float* __restrict__ outb) {
    int e = blockIdx.x * 4 + (threadIdx.x >> 6);
    int lane = threadIdx.x & 63;
    if (e >= ETOT) return;
    int s, d; edge_sd(ei, e, s, d);
    float v = leaky(es[s] + ed[d], ATT_SLOPE);
    float alpha = expf(v - m[d]) / ssum[d];
    float4 hv = *(const float4*)&h[(size_t)s * HDIM + lane * 4];
    float* o = &outb[(size_t)d * HDIM + lane * 4];
    atomicAdd(o + 0, alpha * hv.x);
    atomicAdd(o + 1, alpha * hv.y);
    atomicAdd(o + 2, alpha * hv.z);
    atomicAdd(o + 3, alpha * hv.w);
}

// in-place bias + leaky(0.01) + column sum/sumsq accumulation
__global__ __launch_bounds__(256) void post_bn_stats(float* __restrict__ buf,
                                                     const float* __restrict__ bias,
                                                     float* __restrict__ csum,
                                                     float* __restrict__ csq) {
    int t = threadIdx.x;
    int rows_per = (N_NODES + gridDim.x - 1) / gridDim.x;
    int r0 = blockIdx.x * rows_per;
    int r1 = min(r0 + rows_per, N_NODES);
    float b = bias[t];
    float sum = 0.f, sq = 0.f;
    for (int r = r0; r < r1; ++r) {
        float v = buf[(size_t)r * HDIM + t] + b;
        v = leaky(v, ACT_SLOPE);
        buf[(size_t)r * HDIM + t] = v;
        sum += v; sq += v * v;
    }
    atomicAdd(&csum[t], sum);
    atomicAdd(&csq[t], sq);
}

__global__ __launch_bounds__(256) void bn_param(const float* __restrict__ csum,
                                                const float* __restrict__ csq,
                                                const float* __restrict__ gamma,
                                                const float* __restrict__ beta,
                                                float* __restrict__ scale,
                                                float* __restrict__ shift) {
    int t = threadIdx.x;
    float mean = csum[t] / (float)N_NODES;
    float var = csq[t] / (float)N_NODES - mean * mean;
    float sc = gamma[t] * rsqrtf(var + BN_EPS);
    scale[t] = sc;
    shift[t] = beta[t] - mean * sc;
}

__global__ __launch_bounds__(256) void bn_apply(float* __restrict__ buf,
                                                const float* __restrict__ scale,
                                                const float* __restrict__ shift) {
    size_t i = (size_t)blockIdx.x * 256 + threadIdx.x;
    size_t base = i * 4;
    if (base >= (size_t)N_NODES * HDIM) return;
    int c = (int)(base % HDIM);
    float4 v = *(float4*)&buf[base];
    float4 sc = *(const float4*)&scale[c];
    float4 sh = *(const float4*)&shift[c];
    v.x = v.x * sc.x + sh.x;
    v.y = v.y * sc.y + sh.y;
    v.z = v.z * sc.z + sh.z;
    v.w = v.w * sc.w + sh.w;
    *(float4*)&buf[base] = v;
}

// bias + leaky(0.01) + run-length pooled segment add (batch is sorted)
__global__ __launch_bounds__(256) void post_pool(const float* __restrict__ buf,
                                                 const float* __restrict__ bias,
                                                 const int* __restrict__ batch,
                                                 float* __restrict__ gsum,
                                                 float* __restrict__ gcnt) {
    int t = threadIdx.x;
    int rows_per = (N_NODES + gridDim.x - 1) / gridDim.x;
    int r0 = blockIdx.x * rows_per;
    int r1 = min(r0 + rows_per, N_NODES);
    if (r0 >= r1) return;
    float b = bias[t];
    int curb = -1; float acc = 0.f; int cnt = 0;
    for (int r = r0; r < r1; ++r) {
        int bb = batch[r];
        if (bb != curb) {
            if (curb >= 0) {
                atomicAdd(&gsum[(size_t)curb * HDIM + t], acc);
                if (t == 0) atomicAdd(&gcnt[curb], (float)cnt);
            }
            curb = bb; acc = 0.f; cnt = 0;
        }
        float v = leaky(buf[(size_t)r * HDIM + t] + b, ACT_SLOPE);
        acc += v; cnt++;
    }
    if (curb >= 0) {
        atomicAdd(&gsum[(size_t)curb * HDIM + t], acc);
        if (t == 0) atomicAdd(&gcnt[curb], (float)cnt);
    }
}

// per-graph MLP head
__global__ __launch_bounds__(256) void mlp_head(const float* __restrict__ gsum,
                                                const float* __restrict__ gcnt,
                                                const float* __restrict__ lw1,
                                                const float* __restrict__ lb1,
                                                const float* __restrict__ lw2,
                                                const float* __restrict__ lb2,
                                                float* __restrict__ out) {
    __shared__ float g[HDIM];
    __shared__ float hid[HDIM];
    int b = blockIdx.x, t = threadIdx.x;
    float cnt = fmaxf(gcnt[b], 1.f);
    g[t] = gsum[(size_t)b * HDIM + t] / cnt;
    __syncthreads();
    float acc = lb1[t];
    for (int k = 0; k < HDIM; ++k) acc += g[k] * lw1[(size_t)k * HDIM + t];
    hid[t] = leaky(acc, ACT_SLOPE);
    __syncthreads();
    if (t < C_OUT) {
        float o = lb2[t];
        for (int k = 0; k < HDIM; ++k) o += hid[k] * lw2[(size_t)k * C_OUT + t];
        out[(size_t)b * C_OUT + t] = o;
    }
}

extern "C" void kernel_launch(void* const* d_in, const int* in_sizes, int n_in,
                              void* d_out, int out_size, void* d_ws, size_t ws_size,
                              hipStream_t stream) {
    const float* x      = (const float*)d_in[0];
    const int*   ei     = (const int*)d_in[1];
    const int*   batch  = (const int*)d_in[2];
    const float* W1     = (const float*)d_in[4];
    const float* a_src1 = (const float*)d_in[5];
    const float* a_dst1 = (const float*)d_in[6];
    const float* b1     = (const float*)d_in[7];
    const float* gamma  = (const float*)d_in[8];
    const float* beta   = (const float*)d_in[9];
    const float* W2     = (const float*)d_in[10];
    const float* a_src2 = (const float*)d_in[11];
    const float* a_dst2 = (const float*)d_in[12];
    const float* b2     = (const float*)d_in[13];
    const float* lw1    = (const float*)d_in[14];
    const float* lb1    = (const float*)d_in[15];
    const float* lw2    = (const float*)d_in[16];
    const float* lb2    = (const float*)d_in[17];
    float* out = (float*)d_out;

    const size_t NH = (size_t)N_NODES * HDIM;
    char* ws = (char*)d_ws;
    float* bufA  = (float*)ws; ws += NH * 4;
    float* bufB  = (float*)ws; ws += NH * 4;
    float* e_src = (float*)ws; ws += N_NODES * 4;
    float* e_dst = (float*)ws; ws += N_NODES * 4;
    float* mbuf  = (float*)ws; ws += N_NODES * 4;
    float* sbuf  = (float*)ws; ws += N_NODES * 4;
    float* csum  = (float*)ws; ws += HDIM * 4;
    float* csq   = (float*)ws; ws += HDIM * 4;
    float* scale = (float*)ws; ws += HDIM * 4;
    float* shift = (float*)ws; ws += HDIM * 4;
    float* gsum  = (float*)ws; ws += NGRAPH * HDIM * 4;
    float* gcnt  = (float*)ws; ws += NGRAPH * 4;

    dim3 ggrid((N_NODES + 63) / 64, HDIM / 64);
    const int edge_blocks = (ETOT + 255) / 256;
    const int agg_blocks  = (ETOT + 3) / 4;
    const int node_blocks = (N_NODES + 255) / 256;

    // ---- conv1 ----
    gemm_f32<<<ggrid, 256, 0, stream>>>(x, W1, bufA, N_NODES);
    row_dots<<<(N_NODES + 3) / 4, 256, 0, stream>>>(bufA, a_src1, a_dst1, e_src, e_dst);
    node_init<<<node_blocks, 256, 0, stream>>>(mbuf, sbuf);
    edge_max_k<<<edge_blocks, 256, 0, stream>>>(ei, e_src, e_dst, mbuf);
    edge_sum_k<<<edge_blocks, 256, 0, stream>>>(ei, e_src, e_dst, mbuf, sbuf);
    hipMemsetAsync(bufB, 0, NH * 4, stream);
    edge_agg_k<<<agg_blocks, 256, 0, stream>>>(ei, e_src, e_dst, mbuf, sbuf, bufA, bufB);

    // ---- bias + leaky + BN ----
    hipMemsetAsync(csum, 0, HDIM * 4, stream);
    hipMemsetAsync(csq, 0, HDIM * 4, stream);
    post_bn_stats<<<256, 256, 0, stream>>>(bufB, b1, csum, csq);
    bn_param<<<1, 256, 0, stream>>>(csum, csq, gamma, beta, scale, shift);
    bn_apply<<<(int)((NH / 4 + 255) / 256), 256, 0, stream>>>(bufB, scale, shift);

    // ---- conv2 ----
    gemm_f32<<<ggrid, 256, 0, stream>>>(bufB, W2, bufA, N_NODES);
    row_dots<<<(N_NODES + 3) / 4, 256, 0, stream>>>(bufA, a_src2, a_dst2, e_src, e_dst);
    node_init<<<node_blocks, 256, 0, stream>>>(mbuf, sbuf);
    edge_max_k<<<edge_blocks, 256, 0, stream>>>(ei, e_src, e_dst, mbuf);
    edge_sum_k<<<edge_blocks, 256, 0, stream>>>(ei, e_src, e_dst, mbuf, sbuf);
    hipMemsetAsync(bufB, 0, NH * 4, stream);
    edge_agg_k<<<agg_blocks, 256, 0, stream>>>(ei, e_src, e_dst, mbuf, sbuf, bufA, bufB);

    // ---- bias + leaky + pool ----
    hipMemsetAsync(gsum, 0, (size_t)NGRAPH * HDIM * 4, stream);
    hipMemsetAsync(gcnt, 0, NGRAPH * 4, stream);
    post_pool<<<256, 256, 0, stream>>>(bufB, b2, batch, gsum, gcnt);

    // ---- MLP head ----
    mlp_head<<<NGRAPH, 256, 0, stream>>>(gsum, gcnt, lw1, lb1, lw2, lb2, out);
}

// Round 2
// 917.189 us; speedup vs baseline: 6.7159x; 6.7159x over previous
//
#include <hip/hip_runtime.h>
#include <math.h>

#define N_NODES 50000
#define N_EDGES 800000
#define ETOT    (N_EDGES + N_NODES)
#define FDIM    256
#define HDIM    256
#define NGRAPH  64
#define C_OUT   10
#define BN_EPS  1e-5f
#define ATT_SLOPE 0.2f
#define ACT_SLOPE 0.01f

__device__ __forceinline__ float leaky(float x, float s) { return x >= 0.f ? x : s * x; }

__device__ __forceinline__ void edge_sd(const int* __restrict__ ei, int e, int& s, int& d) {
    if (e < N_EDGES) { s = ei[e]; d = ei[N_EDGES + e]; }
    else             { s = e - N_EDGES; d = s; }
}

// ---------------- GEMM: C[M,256] = A[M,256] @ B[256,256], fp32 ----------------
__global__ __launch_bounds__(256) void gemm_f32(const float* __restrict__ A,
                                                const float* __restrict__ Bw,
                                                float* __restrict__ Cc, int M) {
    __shared__ float As[64][68];
    __shared__ float Bs[64][68];
    const int tid = threadIdx.x;
    const int tx = tid & 15, ty = tid >> 4;
    const int row0 = blockIdx.x * 64, col0 = blockIdx.y * 64;
    float acc[4][4] = {};
    for (int kk = 0; kk < FDIM; kk += 64) {
        const int lr = tid >> 4;          // 0..15
        const int lc4 = (tid & 15) * 4;   // 0..60
        #pragma unroll
        for (int q = 0; q < 4; ++q) {
            int rr = lr + q * 16;
            int grow = row0 + rr;
            float4 av;
            if (grow < M) av = *(const float4*)&A[(size_t)grow * FDIM + kk + lc4];
            else          av = make_float4(0.f, 0.f, 0.f, 0.f);
            *(float4*)&As[rr][lc4] = av;
            float4 bv = *(const float4*)&Bw[(size_t)(kk + rr) * HDIM + col0 + lc4];
            *(float4*)&Bs[rr][lc4] = bv;
        }
        __syncthreads();
        #pragma unroll 8
        for (int k = 0; k < 64; ++k) {
            float a0 = As[ty * 4 + 0][k];
            float a1 = As[ty * 4 + 1][k];
            float a2 = As[ty * 4 + 2][k];
            float a3 = As[ty * 4 + 3][k];
            float4 b4 = *(float4*)&Bs[k][tx * 4];
            acc[0][0] += a0 * b4.x; acc[0][1] += a0 * b4.y; acc[0][2] += a0 * b4.z; acc[0][3] += a0 * b4.w;
            acc[1][0] += a1 * b4.x; acc[1][1] += a1 * b4.y; acc[1][2] += a1 * b4.z; acc[1][3] += a1 * b4.w;
            acc[2][0] += a2 * b4.x; acc[2][1] += a2 * b4.y; acc[2][2] += a2 * b4.z; acc[2][3] += a2 * b4.w;
            acc[3][0] += a3 * b4.x; acc[3][1] += a3 * b4.y; acc[3][2] += a3 * b4.z; acc[3][3] += a3 * b4.w;
        }
        __syncthreads();
    }
    #pragma unroll
    for (int i = 0; i < 4; ++i) {
        int grow = row0 + ty * 4 + i;
        if (grow < M) {
            float4 v = make_float4(acc[i][0], acc[i][1], acc[i][2], acc[i][3]);
            *(float4*)&Cc[(size_t)grow * HDIM + col0 + tx * 4] = v;
        }
    }
}

// ------------- per-row dual dot: e_src[i]=h[i].a_src, e_dst[i]=h[i].a_dst -------------
__global__ __launch_bounds__(256) void row_dots(const float* __restrict__ h,
                                                const float* __restrict__ av_s,
                                                const float* __restrict__ av_d,
                                                float* __restrict__ es, float* __restrict__ ed) {
    int row = blockIdx.x * 4 + (threadIdx.x >> 6);
    int lane = threadIdx.x & 63;
    if (row >= N_NODES) return;
    float4 hv = *(const float4*)&h[(size_t)row * HDIM + lane * 4];
    float4 s4 = *(const float4*)&av_s[lane * 4];
    float4 d4 = *(const float4*)&av_d[lane * 4];
    float vs = hv.x * s4.x + hv.y * s4.y + hv.z * s4.z + hv.w * s4.w;
    float vd = hv.x * d4.x + hv.y * d4.y + hv.z * d4.z + hv.w * d4.w;
    #pragma unroll
    for (int off = 32; off; off >>= 1) {
        vs += __shfl_down(vs, off);
        vd += __shfl_down(vd, off);
    }
    if (lane == 0) { es[row] = vs; ed[row] = vd; }
}

// ---------------- CSR build: histogram -> scan -> scatter ----------------
__global__ __launch_bounds__(256) void hist_k(const int* __restrict__ ei, int* __restrict__ hist) {
    int e = blockIdx.x * 256 + threadIdx.x;
    if (e >= ETOT) return;
    int s, d; edge_sd(ei, e, s, d);
    atomicAdd(&hist[d], 1);
}

__global__ __launch_bounds__(256) void scan_k(const int* __restrict__ hist,
                                              int* __restrict__ row_ptr,
                                              int* __restrict__ cursor) {
    __shared__ int sdata[256];
    __shared__ int carry_s;
    int t = threadIdx.x;
    if (t == 0) carry_s = 0;
    __syncthreads();
    for (int base = 0; base < N_NODES; base += 256) {
        int i = base + t;
        int v = (i < N_NODES) ? hist[i] : 0;
        sdata[t] = v;
        __syncthreads();
        #pragma unroll
        for (int off = 1; off < 256; off <<= 1) {
            int add = (t >= off) ? sdata[t - off] : 0;
            __syncthreads();
            sdata[t] += add;
            __syncthreads();
        }
        int incl = sdata[t];
        int excl = carry_s + incl - v;
        if (i < N_NODES) { row_ptr[i] = excl; cursor[i] = excl; }
        __syncthreads();
        if (t == 255) carry_s += incl;
        __syncthreads();
    }
    if (t == 0) row_ptr[N_NODES] = carry_s;
}

__global__ __launch_bounds__(256) void scatter_k(const int* __restrict__ ei,
                                                 int* __restrict__ cursor,
                                                 int* __restrict__ csr_src) {
    int e = blockIdx.x * 256 + threadIdx.x;
    if (e >= ETOT) return;
    int s, d; edge_sd(ei, e, s, d);
    int pos = atomicAdd(&cursor[d], 1);
    csr_src[pos] = s;
}

// ---------------- fused per-dst softmax + gather aggregation ----------------
// one wave per destination node; lane covers 4 features
__global__ __launch_bounds__(256) void dst_agg(const int* __restrict__ row_ptr,
                                               const int* __restrict__ csr_src,
                                               const float* __restrict__ es,
                                               const float* __restrict__ ed,
                                               const float* __restrict__ h,
                                               float* __restrict__ outb) {
    int d = blockIdx.x * 4 + (threadIdx.x >> 6);
    int lane = threadIdx.x & 63;
    if (d >= N_NODES) return;
    int start = row_ptr[d], end = row_ptr[d + 1];
    if (start >= end) {  // can't happen (self-loops) but stay safe
        *(float4*)&outb[(size_t)d * HDIM + lane * 4] = make_float4(0, 0, 0, 0);
        return;
    }
    float edv = ed[d];
    // pass 1: max over incident edges
    float m = -INFINITY;
    for (int base = start; base < end; base += 64) {
        int idx = base + lane;
        if (idx < end) {
            float v = leaky(es[csr_src[idx]] + edv, ATT_SLOPE);
            m = fmaxf(m, v);
        }
    }
    #pragma unroll
    for (int off = 32; off; off >>= 1) m = fmaxf(m, __shfl_xor(m, off));
    // pass 2: exp-weights + weighted gather accumulate
    float ssum = 0.f;
    float4 acc = make_float4(0.f, 0.f, 0.f, 0.f);
    for (int base = start; base < end; base += 64) {
        int idx = base + lane;
        int src = 0; float a = 0.f;
        if (idx < end) {
            src = csr_src[idx];
            a = expf(leaky(es[src] + edv, ATT_SLOPE) - m);
        }
        ssum += a;
        int lim = min(64, end - base);
        for (int j = 0; j < lim; ++j) {
            float aj = __shfl(a, j);
            int sj = __shfl(src, j);
            const float4 hv = *(const float4*)&h[(size_t)sj * HDIM + lane * 4];
            acc.x += aj * hv.x; acc.y += aj * hv.y;
            acc.z += aj * hv.z; acc.w += aj * hv.w;
        }
    }
    #pragma unroll
    for (int off = 32; off; off >>= 1) ssum += __shfl_xor(ssum, off);
    float inv = 1.f / ssum;
    float4 o = make_float4(acc.x * inv, acc.y * inv, acc.z * inv, acc.w * inv);
    *(float4*)&outb[(size_t)d * HDIM + lane * 4] = o;
}

// in-place bias + leaky(0.01) + column sum/sumsq accumulation
__global__ __launch_bounds__(256) void post_bn_stats(float* __restrict__ buf,
                                                     const float* __restrict__ bias,
                                                     float* __restrict__ csum,
                                                     float* __restrict__ csq) {
    int t = threadIdx.x;
    int rows_per = (N_NODES + gridDim.x - 1) / gridDim.x;
    int r0 = blockIdx.x * rows_per;
    int r1 = min(r0 + rows_per, N_NODES);
    float b = bias[t];
    float sum = 0.f, sq = 0.f;
    for (int r = r0; r < r1; ++r) {
        float v = buf[(size_t)r * HDIM + t] + b;
        v = leaky(v, ACT_SLOPE);
        buf[(size_t)r * HDIM + t] = v;
        sum += v; sq += v * v;
    }
    atomicAdd(&csum[t], sum);
    atomicAdd(&csq[t], sq);
}

__global__ __launch_bounds__(256) void bn_param(const float* __restrict__ csum,
                                                const float* __restrict__ csq,
                                                const float* __restrict__ gamma,
                                                const float* __restrict__ beta,
                                                float* __restrict__ scale,
                                                float* __restrict__ shift) {
    int t = threadIdx.x;
    float mean = csum[t] / (float)N_NODES;
    float var = csq[t] / (float)N_NODES - mean * mean;
    float sc = gamma[t] * rsqrtf(var + BN_EPS);
    scale[t] = sc;
    shift[t] = beta[t] - mean * sc;
}

__global__ __launch_bounds__(256) void bn_apply(float* __restrict__ buf,
                                                const float* __restrict__ scale,
                                                const float* __restrict__ shift) {
    size_t i = (size_t)blockIdx.x * 256 + threadIdx.x;
    size_t base = i * 4;
    if (base >= (size_t)N_NODES * HDIM) return;
    int c = (int)(base % HDIM);
    float4 v = *(float4*)&buf[base];
    float4 sc = *(const float4*)&scale[c];
    float4 sh = *(const float4*)&shift[c];
    v.x = v.x * sc.x + sh.x;
    v.y = v.y * sc.y + sh.y;
    v.z = v.z * sc.z + sh.z;
    v.w = v.w * sc.w + sh.w;
    *(float4*)&buf[base] = v;
}

// bias + leaky(0.01) + run-length pooled segment add (batch is sorted)
__global__ __launch_bounds__(256) void post_pool(const float* __restrict__ buf,
                                                 const float* __restrict__ bias,
                                                 const int* __restrict__ batch,
                                                 float* __restrict__ gsum,
                                                 float* __restrict__ gcnt) {
    int t = threadIdx.x;
    int rows_per = (N_NODES + gridDim.x - 1) / gridDim.x;
    int r0 = blockIdx.x * rows_per;
    int r1 = min(r0 + rows_per, N_NODES);
    if (r0 >= r1) return;
    float b = bias[t];
    int curb = -1; float acc = 0.f; int cnt = 0;
    for (int r = r0; r < r1; ++r) {
        int bb = batch[r];
        if (bb != curb) {
            if (curb >= 0) {
                atomicAdd(&gsum[(size_t)curb * HDIM + t], acc);
                if (t == 0) atomicAdd(&gcnt[curb], (float)cnt);
            }
            curb = bb; acc = 0.f; cnt = 0;
        }
        float v = leaky(buf[(size_t)r * HDIM + t] + b, ACT_SLOPE);
        acc += v; cnt++;
    }
    if (curb >= 0) {
        atomicAdd(&gsum[(size_t)curb * HDIM + t], acc);
        if (t == 0) atomicAdd(&gcnt[curb], (float)cnt);
    }
}

// per-graph MLP head
__global__ __launch_bounds__(256) void mlp_head(const float* __restrict__ gsum,
                                                const float* __restrict__ gcnt,
                                                const float* __restrict__ lw1,
                                                const float* __restrict__ lb1,
                                                const float* __restrict__ lw2,
                                                const float* __restrict__ lb2,
                                                float* __restrict__ out) {
    __shared__ float g[HDIM];
    __shared__ float hid[HDIM];
    int b = blockIdx.x, t = threadIdx.x;
    float cnt = fmaxf(gcnt[b], 1.f);
    g[t] = gsum[(size_t)b * HDIM + t] / cnt;
    __syncthreads();
    float acc = lb1[t];
    for (int k = 0; k < HDIM; ++k) acc += g[k] * lw1[(size_t)k * HDIM + t];
    hid[t] = leaky(acc, ACT_SLOPE);
    __syncthreads();
    if (t < C_OUT) {
        float o = lb2[t];
        for (int k = 0; k < HDIM; ++k) o += hid[k] * lw2[(size_t)k * C_OUT + t];
        out[(size_t)b * C_OUT + t] = o;
    }
}

extern "C" void kernel_launch(void* const* d_in, const int* in_sizes, int n_in,
                              void* d_out, int out_size, void* d_ws, size_t ws_size,
                              hipStream_t stream) {
    const float* x      = (const float*)d_in[0];
    const int*   ei     = (const int*)d_in[1];
    const int*   batch  = (const int*)d_in[2];
    const float* W1     = (const float*)d_in[4];
    const float* a_src1 = (const float*)d_in[5];
    const float* a_dst1 = (const float*)d_in[6];
    const float* b1     = (const float*)d_in[7];
    const float* gamma  = (const float*)d_in[8];
    const float* beta   = (const float*)d_in[9];
    const float* W2     = (const float*)d_in[10];
    const float* a_src2 = (const float*)d_in[11];
    const float* a_dst2 = (const float*)d_in[12];
    const float* b2     = (const float*)d_in[13];
    const float* lw1    = (const float*)d_in[14];
    const float* lb1    = (const float*)d_in[15];
    const float* lw2    = (const float*)d_in[16];
    const float* lb2    = (const float*)d_in[17];
    float* out = (float*)d_out;

    const size_t NH = (size_t)N_NODES * HDIM;
    char* ws = (char*)d_ws;
    float* bufA    = (float*)ws; ws += NH * 4;
    float* bufB    = (float*)ws; ws += NH * 4;
    float* e_src   = (float*)ws; ws += N_NODES * 4;
    float* e_dst   = (float*)ws; ws += N_NODES * 4;
    float* csum    = (float*)ws; ws += HDIM * 4;
    float* csq     = (float*)ws; ws += HDIM * 4;
    float* scale   = (float*)ws; ws += HDIM * 4;
    float* shift   = (float*)ws; ws += HDIM * 4;
    float* gsum    = (float*)ws; ws += NGRAPH * HDIM * 4;
    float* gcnt    = (float*)ws; ws += NGRAPH * 4;
    int*   hist    = (int*)ws;   ws += N_NODES * 4;
    int*   row_ptr = (int*)ws;   ws += (N_NODES + 1) * 4;
    int*   cursor  = (int*)ws;   ws += N_NODES * 4;
    int*   csr_src = (int*)ws;   ws += (size_t)ETOT * 4;

    dim3 ggrid((N_NODES + 63) / 64, HDIM / 64);
    const int edge_blocks = (ETOT + 255) / 256;
    const int node_blocks = (N_NODES + 255) / 256;
    const int wave4_blocks = (N_NODES + 3) / 4;

    // ---- CSR build (once; shared by both convs) ----
    hipMemsetAsync(hist, 0, N_NODES * 4, stream);
    hist_k<<<edge_blocks, 256, 0, stream>>>(ei, hist);
    scan_k<<<1, 256, 0, stream>>>(hist, row_ptr, cursor);
    scatter_k<<<edge_blocks, 256, 0, stream>>>(ei, cursor, csr_src);

    // ---- conv1 ----
    gemm_f32<<<ggrid, 256, 0, stream>>>(x, W1, bufA, N_NODES);
    row_dots<<<wave4_blocks, 256, 0, stream>>>(bufA, a_src1, a_dst1, e_src, e_dst);
    dst_agg<<<wave4_blocks, 256, 0, stream>>>(row_ptr, csr_src, e_src, e_dst, bufA, bufB);

    // ---- bias + leaky + BN ----
    hipMemsetAsync(csum, 0, HDIM * 4, stream);
    hipMemsetAsync(csq, 0, HDIM * 4, stream);
    post_bn_stats<<<256, 256, 0, stream>>>(bufB, b1, csum, csq);
    bn_param<<<1, 256, 0, stream>>>(csum, csq, gamma, beta, scale, shift);
    bn_apply<<<(int)((NH / 4 + 255) / 256), 256, 0, stream>>>(bufB, scale, shift);

    // ---- conv2 ----
    gemm_f32<<<ggrid, 256, 0, stream>>>(bufB, W2, bufA, N_NODES);
    row_dots<<<wave4_blocks, 256, 0, stream>>>(bufA, a_src2, a_dst2, e_src, e_dst);
    dst_agg<<<wave4_blocks, 256, 0, stream>>>(row_ptr, csr_src, e_src, e_dst, bufA, bufB);

    // ---- bias + leaky + pool ----
    hipMemsetAsync(gsum, 0, (size_t)NGRAPH * HDIM * 4, stream);
    hipMemsetAsync(gcnt, 0, NGRAPH * 4, stream);
    post_pool<<<256, 256, 0, stream>>>(bufB, b2, batch, gsum, gcnt);

    // ---- MLP head ----
    mlp_head<<<NGRAPH, 256, 0, stream>>>(gsum, gcnt, lw1, lb1, lw2, lb2, out);
}

// Round 3
// 702.599 us; speedup vs baseline: 8.7670x; 1.3054x over previous
//
#include <hip/hip_runtime.h>
#include <math.h>

#define N_NODES 50000
#define N_EDGES 800000
#define ETOT    (N_EDGES + N_NODES)
#define FDIM    256
#define HDIM    256
#define NGRAPH  64
#define C_OUT   10
#define BN_EPS  1e-5f
#define ATT_SLOPE 0.2f
#define ACT_SLOPE 0.01f

#define SCAN_NB ((N_NODES + 255) / 256)   // 196

__device__ __forceinline__ float leaky(float x, float s) { return x >= 0.f ? x : s * x; }

__device__ __forceinline__ void edge_sd(const int* __restrict__ ei, int e, int& s, int& d) {
    if (e < N_EDGES) { s = ei[e]; d = ei[N_EDGES + e]; }
    else             { s = e - N_EDGES; d = s; }
}

// ---------------- GEMM: C[M,256] = A[M,256] @ B[256,256], fp32 ----------------
__global__ __launch_bounds__(256) void gemm_f32(const float* __restrict__ A,
                                                const float* __restrict__ Bw,
                                                float* __restrict__ Cc, int M) {
    __shared__ float As[64][68];
    __shared__ float Bs[64][68];
    const int tid = threadIdx.x;
    const int tx = tid & 15, ty = tid >> 4;
    const int row0 = blockIdx.x * 64, col0 = blockIdx.y * 64;
    float acc[4][4] = {};
    for (int kk = 0; kk < FDIM; kk += 64) {
        const int lr = tid >> 4;          // 0..15
        const int lc4 = (tid & 15) * 4;   // 0..60
        #pragma unroll
        for (int q = 0; q < 4; ++q) {
            int rr = lr + q * 16;
            int grow = row0 + rr;
            float4 av;
            if (grow < M) av = *(const float4*)&A[(size_t)grow * FDIM + kk + lc4];
            else          av = make_float4(0.f, 0.f, 0.f, 0.f);
            *(float4*)&As[rr][lc4] = av;
            float4 bv = *(const float4*)&Bw[(size_t)(kk + rr) * HDIM + col0 + lc4];
            *(float4*)&Bs[rr][lc4] = bv;
        }
        __syncthreads();
        #pragma unroll 8
        for (int k = 0; k < 64; ++k) {
            float a0 = As[ty * 4 + 0][k];
            float a1 = As[ty * 4 + 1][k];
            float a2 = As[ty * 4 + 2][k];
            float a3 = As[ty * 4 + 3][k];
            float4 b4 = *(float4*)&Bs[k][tx * 4];
            acc[0][0] += a0 * b4.x; acc[0][1] += a0 * b4.y; acc[0][2] += a0 * b4.z; acc[0][3] += a0 * b4.w;
            acc[1][0] += a1 * b4.x; acc[1][1] += a1 * b4.y; acc[1][2] += a1 * b4.z; acc[1][3] += a1 * b4.w;
            acc[2][0] += a2 * b4.x; acc[2][1] += a2 * b4.y; acc[2][2] += a2 * b4.z; acc[2][3] += a2 * b4.w;
            acc[3][0] += a3 * b4.x; acc[3][1] += a3 * b4.y; acc[3][2] += a3 * b4.z; acc[3][3] += a3 * b4.w;
        }
        __syncthreads();
    }
    #pragma unroll
    for (int i = 0; i < 4; ++i) {
        int grow = row0 + ty * 4 + i;
        if (grow < M) {
            float4 v = make_float4(acc[i][0], acc[i][1], acc[i][2], acc[i][3]);
            *(float4*)&Cc[(size_t)grow * HDIM + col0 + tx * 4] = v;
        }
    }
}

// ------------- per-row dual dot: e_src[i]=h[i].a_src, e_dst[i]=h[i].a_dst -------------
__global__ __launch_bounds__(256) void row_dots(const float* __restrict__ h,
                                                const float* __restrict__ av_s,
                                                const float* __restrict__ av_d,
                                                float* __restrict__ es, float* __restrict__ ed) {
    int row = blockIdx.x * 4 + (threadIdx.x >> 6);
    int lane = threadIdx.x & 63;
    if (row >= N_NODES) return;
    float4 hv = *(const float4*)&h[(size_t)row * HDIM + lane * 4];
    float4 s4 = *(const float4*)&av_s[lane * 4];
    float4 d4 = *(const float4*)&av_d[lane * 4];
    float vs = hv.x * s4.x + hv.y * s4.y + hv.z * s4.z + hv.w * s4.w;
    float vd = hv.x * d4.x + hv.y * d4.y + hv.z * d4.z + hv.w * d4.w;
    #pragma unroll
    for (int off = 32; off; off >>= 1) {
        vs += __shfl_down(vs, off);
        vd += __shfl_down(vd, off);
    }
    if (lane == 0) { es[row] = vs; ed[row] = vd; }
}

// ---------------- CSR build: histogram -> hierarchical scan -> scatter ----------------
__global__ __launch_bounds__(256) void hist_k(const int* __restrict__ ei, int* __restrict__ hist) {
    int e = blockIdx.x * 256 + threadIdx.x;
    if (e >= ETOT) return;
    int s, d; edge_sd(ei, e, s, d);
    atomicAdd(&hist[d], 1);
}

// level A: per-block (256-elem chunk) sum
__global__ __launch_bounds__(256) void scan_bsum_k(const int* __restrict__ hist,
                                                   int* __restrict__ bsum) {
    __shared__ int sdata[256];
    int t = threadIdx.x;
    int i = blockIdx.x * 256 + t;
    sdata[t] = (i < N_NODES) ? hist[i] : 0;
    __syncthreads();
    #pragma unroll
    for (int off = 128; off; off >>= 1) {
        if (t < off) sdata[t] += sdata[t + off];
        __syncthreads();
    }
    if (t == 0) bsum[blockIdx.x] = sdata[0];
}

// level B: exclusive scan of the 196 block sums (one block)
__global__ __launch_bounds__(256) void scan_boff_k(const int* __restrict__ bsum,
                                                   int* __restrict__ boff) {
    __shared__ int sdata[256];
    int t = threadIdx.x;
    int v = (t < SCAN_NB) ? bsum[t] : 0;
    sdata[t] = v;
    __syncthreads();
    #pragma unroll
    for (int off = 1; off < 256; off <<= 1) {
        int add = (t >= off) ? sdata[t - off] : 0;
        __syncthreads();
        sdata[t] += add;
        __syncthreads();
    }
    if (t < SCAN_NB) boff[t] = sdata[t] - v;  // exclusive
}

// level C: in-block scan + offset -> row_ptr & cursor
__global__ __launch_bounds__(256) void scan_final_k(const int* __restrict__ hist,
                                                    const int* __restrict__ boff,
                                                    int* __restrict__ row_ptr,
                                                    int* __restrict__ cursor) {
    __shared__ int sdata[256];
    int t = threadIdx.x;
    int i = blockIdx.x * 256 + t;
    int v = (i < N_NODES) ? hist[i] : 0;
    sdata[t] = v;
    __syncthreads();
    #pragma unroll
    for (int off = 1; off < 256; off <<= 1) {
        int add = (t >= off) ? sdata[t - off] : 0;
        __syncthreads();
        sdata[t] += add;
        __syncthreads();
    }
    int excl = boff[blockIdx.x] + sdata[t] - v;
    if (i <= N_NODES) {             // i == N_NODES writes the total (= ETOT)
        row_ptr[i] = excl;
        if (i < N_NODES) cursor[i] = excl;
    }
}

__global__ __launch_bounds__(256) void scatter_k(const int* __restrict__ ei,
                                                 int* __restrict__ cursor,
                                                 int* __restrict__ csr_src) {
    int e = blockIdx.x * 256 + threadIdx.x;
    if (e >= ETOT) return;
    int s, d; edge_sd(ei, e, s, d);
    int pos = atomicAdd(&cursor[d], 1);
    csr_src[pos] = s;
}

// ---------------- fused per-dst softmax + gather aggregation ----------------
// one wave per destination node; lane covers 4 features
__global__ __launch_bounds__(256) void dst_agg(const int* __restrict__ row_ptr,
                                               const int* __restrict__ csr_src,
                                               const float* __restrict__ es,
                                               const float* __restrict__ ed,
                                               const float* __restrict__ h,
                                               float* __restrict__ outb) {
    int d = blockIdx.x * 4 + (threadIdx.x >> 6);
    int lane = threadIdx.x & 63;
    if (d >= N_NODES) return;
    int start = row_ptr[d], end = row_ptr[d + 1];
    if (start >= end) {
        *(float4*)&outb[(size_t)d * HDIM + lane * 4] = make_float4(0, 0, 0, 0);
        return;
    }
    float edv = ed[d];
    // pass 1: max over incident edges
    float m = -INFINITY;
    for (int base = start; base < end; base += 64) {
        int idx = base + lane;
        if (idx < end) {
            float v = leaky(es[csr_src[idx]] + edv, ATT_SLOPE);
            m = fmaxf(m, v);
        }
    }
    #pragma unroll
    for (int off = 32; off; off >>= 1) m = fmaxf(m, __shfl_xor(m, off));
    // pass 2: exp-weights + weighted gather accumulate
    float ssum = 0.f;
    float4 acc = make_float4(0.f, 0.f, 0.f, 0.f);
    for (int base = start; base < end; base += 64) {
        int idx = base + lane;
        int src = 0; float a = 0.f;
        if (idx < end) {
            src = csr_src[idx];
            a = expf(leaky(es[src] + edv, ATT_SLOPE) - m);
        }
        ssum += a;
        int lim = min(64, end - base);
        for (int j = 0; j < lim; ++j) {
            float aj = __shfl(a, j);
            int sj = __shfl(src, j);
            const float4 hv = *(const float4*)&h[(size_t)sj * HDIM + lane * 4];
            acc.x += aj * hv.x; acc.y += aj * hv.y;
            acc.z += aj * hv.z; acc.w += aj * hv.w;
        }
    }
    #pragma unroll
    for (int off = 32; off; off >>= 1) ssum += __shfl_xor(ssum, off);
    float inv = 1.f / ssum;
    float4 o = make_float4(acc.x * inv, acc.y * inv, acc.z * inv, acc.w * inv);
    *(float4*)&outb[(size_t)d * HDIM + lane * 4] = o;
}

// in-place bias + leaky(0.01) + column sum/sumsq accumulation
__global__ __launch_bounds__(256) void post_bn_stats(float* __restrict__ buf,
                                                     const float* __restrict__ bias,
                                                     float* __restrict__ csum,
                                                     float* __restrict__ csq) {
    int t = threadIdx.x;
    int rows_per = (N_NODES + gridDim.x - 1) / gridDim.x;
    int r0 = blockIdx.x * rows_per;
    int r1 = min(r0 + rows_per, N_NODES);
    float b = bias[t];
    float sum = 0.f, sq = 0.f;
    for (int r = r0; r < r1; ++r) {
        float v = buf[(size_t)r * HDIM + t] + b;
        v = leaky(v, ACT_SLOPE);
        buf[(size_t)r * HDIM + t] = v;
        sum += v; sq += v * v;
    }
    atomicAdd(&csum[t], sum);
    atomicAdd(&csq[t], sq);
}

__global__ __launch_bounds__(256) void bn_param(const float* __restrict__ csum,
                                                const float* __restrict__ csq,
                                                const float* __restrict__ gamma,
                                                const float* __restrict__ beta,
                                                float* __restrict__ scale,
                                                float* __restrict__ shift) {
    int t = threadIdx.x;
    float mean = csum[t] / (float)N_NODES;
    float var = csq[t] / (float)N_NODES - mean * mean;
    float sc = gamma[t] * rsqrtf(var + BN_EPS);
    scale[t] = sc;
    shift[t] = beta[t] - mean * sc;
}

__global__ __launch_bounds__(256) void bn_apply(float* __restrict__ buf,
                                                const float* __restrict__ scale,
                                                const float* __restrict__ shift) {
    size_t i = (size_t)blockIdx.x * 256 + threadIdx.x;
    size_t base = i * 4;
    if (base >= (size_t)N_NODES * HDIM) return;
    int c = (int)(base % HDIM);
    float4 v = *(float4*)&buf[base];
    float4 sc = *(const float4*)&scale[c];
    float4 sh = *(const float4*)&shift[c];
    v.x = v.x * sc.x + sh.x;
    v.y = v.y * sc.y + sh.y;
    v.z = v.z * sc.z + sh.z;
    v.w = v.w * sc.w + sh.w;
    *(float4*)&buf[base] = v;
}

// bias + leaky(0.01) + run-length pooled segment add (batch is sorted)
__global__ __launch_bounds__(256) void post_pool(const float* __restrict__ buf,
                                                 const float* __restrict__ bias,
                                                 const int* __restrict__ batch,
                                                 float* __restrict__ gsum,
                                                 float* __restrict__ gcnt) {
    int t = threadIdx.x;
    int rows_per = (N_NODES + gridDim.x - 1) / gridDim.x;
    int r0 = blockIdx.x * rows_per;
    int r1 = min(r0 + rows_per, N_NODES);
    if (r0 >= r1) return;
    float b = bias[t];
    int curb = -1; float acc = 0.f; int cnt = 0;
    for (int r = r0; r < r1; ++r) {
        int bb = batch[r];
        if (bb != curb) {
            if (curb >= 0) {
                atomicAdd(&gsum[(size_t)curb * HDIM + t], acc);
                if (t == 0) atomicAdd(&gcnt[curb], (float)cnt);
            }
            curb = bb; acc = 0.f; cnt = 0;
        }
        float v = leaky(buf[(size_t)r * HDIM + t] + b, ACT_SLOPE);
        acc += v; cnt++;
    }
    if (curb >= 0) {
        atomicAdd(&gsum[(size_t)curb * HDIM + t], acc);
        if (t == 0) atomicAdd(&gcnt[curb], (float)cnt);
    }
}

// per-graph MLP head
__global__ __launch_bounds__(256) void mlp_head(const float* __restrict__ gsum,
                                                const float* __restrict__ gcnt,
                                                const float* __restrict__ lw1,
                                                const float* __restrict__ lb1,
                                                const float* __restrict__ lw2,
                                                const float* __restrict__ lb2,
                                                float* __restrict__ out) {
    __shared__ float g[HDIM];
    __shared__ float hid[HDIM];
    int b = blockIdx.x, t = threadIdx.x;
    float cnt = fmaxf(gcnt[b], 1.f);
    g[t] = gsum[(size_t)b * HDIM + t] / cnt;
    __syncthreads();
    float acc = lb1[t];
    for (int k = 0; k < HDIM; ++k) acc += g[k] * lw1[(size_t)k * HDIM + t];
    hid[t] = leaky(acc, ACT_SLOPE);
    __syncthreads();
    if (t < C_OUT) {
        float o = lb2[t];
        for (int k = 0; k < HDIM; ++k) o += hid[k] * lw2[(size_t)k * C_OUT + t];
        out[(size_t)b * C_OUT + t] = o;
    }
}

extern "C" void kernel_launch(void* const* d_in, const int* in_sizes, int n_in,
                              void* d_out, int out_size, void* d_ws, size_t ws_size,
                              hipStream_t stream) {
    const float* x      = (const float*)d_in[0];
    const int*   ei     = (const int*)d_in[1];
    const int*   batch  = (const int*)d_in[2];
    const float* W1     = (const float*)d_in[4];
    const float* a_src1 = (const float*)d_in[5];
    const float* a_dst1 = (const float*)d_in[6];
    const float* b1     = (const float*)d_in[7];
    const float* gamma  = (const float*)d_in[8];
    const float* beta   = (const float*)d_in[9];
    const float* W2     = (const float*)d_in[10];
    const float* a_src2 = (const float*)d_in[11];
    const float* a_dst2 = (const float*)d_in[12];
    const float* b2     = (const float*)d_in[13];
    const float* lw1    = (const float*)d_in[14];
    const float* lb1    = (const float*)d_in[15];
    const float* lw2    = (const float*)d_in[16];
    const float* lb2    = (const float*)d_in[17];
    float* out = (float*)d_out;

    const size_t NH = (size_t)N_NODES * HDIM;
    char* ws = (char*)d_ws;
    float* bufA    = (float*)ws; ws += NH * 4;
    float* bufB    = (float*)ws; ws += NH * 4;
    float* e_src   = (float*)ws; ws += N_NODES * 4;
    float* e_dst   = (float*)ws; ws += N_NODES * 4;
    float* csum    = (float*)ws; ws += HDIM * 4;
    float* csq     = (float*)ws; ws += HDIM * 4;
    float* scale   = (float*)ws; ws += HDIM * 4;
    float* shift   = (float*)ws; ws += HDIM * 4;
    float* gsum    = (float*)ws; ws += NGRAPH * HDIM * 4;
    float* gcnt    = (float*)ws; ws += NGRAPH * 4;
    int*   hist    = (int*)ws;   ws += N_NODES * 4;
    int*   row_ptr = (int*)ws;   ws += (N_NODES + 1) * 4;
    int*   cursor  = (int*)ws;   ws += N_NODES * 4;
    int*   bsum    = (int*)ws;   ws += SCAN_NB * 4;
    int*   boff    = (int*)ws;   ws += SCAN_NB * 4;
    int*   csr_src = (int*)ws;   ws += (size_t)ETOT * 4;

    dim3 ggrid((N_NODES + 63) / 64, HDIM / 64);
    const int edge_blocks = (ETOT + 255) / 256;
    const int wave4_blocks = (N_NODES + 3) / 4;

    // ---- CSR build (once; shared by both convs) ----
    hipMemsetAsync(hist, 0, N_NODES * 4, stream);
    hist_k<<<edge_blocks, 256, 0, stream>>>(ei, hist);
    scan_bsum_k<<<SCAN_NB, 256, 0, stream>>>(hist, bsum);
    scan_boff_k<<<1, 256, 0, stream>>>(bsum, boff);
    scan_final_k<<<SCAN_NB, 256, 0, stream>>>(hist, boff, row_ptr, cursor);
    scatter_k<<<edge_blocks, 256, 0, stream>>>(ei, cursor, csr_src);

    // ---- conv1 ----
    gemm_f32<<<ggrid, 256, 0, stream>>>(x, W1, bufA, N_NODES);
    row_dots<<<wave4_blocks, 256, 0, stream>>>(bufA, a_src1, a_dst1, e_src, e_dst);
    dst_agg<<<wave4_blocks, 256, 0, stream>>>(row_ptr, csr_src, e_src, e_dst, bufA, bufB);

    // ---- bias + leaky + BN ----
    hipMemsetAsync(csum, 0, HDIM * 4, stream);
    hipMemsetAsync(csq, 0, HDIM * 4, stream);
    post_bn_stats<<<256, 256, 0, stream>>>(bufB, b1, csum, csq);
    bn_param<<<1, 256, 0, stream>>>(csum, csq, gamma, beta, scale, shift);
    bn_apply<<<(int)((NH / 4 + 255) / 256), 256, 0, stream>>>(bufB, scale, shift);

    // ---- conv2 ----
    gemm_f32<<<ggrid, 256, 0, stream>>>(bufB, W2, bufA, N_NODES);
    row_dots<<<wave4_blocks, 256, 0, stream>>>(bufA, a_src2, a_dst2, e_src, e_dst);
    dst_agg<<<wave4_blocks, 256, 0, stream>>>(row_ptr, csr_src, e_src, e_dst, bufA, bufB);

    // ---- bias + leaky + pool ----
    hipMemsetAsync(gsum, 0, (size_t)NGRAPH * HDIM * 4, stream);
    hipMemsetAsync(gcnt, 0, NGRAPH * 4, stream);
    post_pool<<<256, 256, 0, stream>>>(bufB, b2, batch, gsum, gcnt);

    // ---- MLP head ----
    mlp_head<<<NGRAPH, 256, 0, stream>>>(gsum, gcnt, lw1, lb1, lw2, lb2, out);
}

// Round 4
// 472.952 us; speedup vs baseline: 13.0240x; 1.4856x over previous
//
#include <hip/hip_runtime.h>
#include <math.h>

#define N_NODES 50000
#define N_EDGES 800000
#define ETOT    (N_EDGES + N_NODES)
#define FDIM    256
#define HDIM    256
#define NGRAPH  64
#define C_OUT   10
#define BN_EPS  1e-5f
#define ATT_SLOPE 0.2f
#define ACT_SLOPE 0.01f

#define SCAN_NB ((N_NODES + 255) / 256)   // 196

typedef __attribute__((ext_vector_type(8))) short bf16x8;
typedef __attribute__((ext_vector_type(4))) float f32x4;

__device__ __forceinline__ float leaky(float x, float s) { return x >= 0.f ? x : s * x; }

__device__ __forceinline__ float bf2f(unsigned short u) {
    return __uint_as_float((unsigned)u << 16);
}
__device__ __forceinline__ unsigned short f2bf(float f) {
    unsigned u = __float_as_uint(f);
    u += 0x7FFF + ((u >> 16) & 1);   // RNE
    return (unsigned short)(u >> 16);
}

__device__ __forceinline__ void edge_sd(const int* __restrict__ ei, int e, int& s, int& d) {
    if (e < N_EDGES) { s = ei[e]; d = ei[N_EDGES + e]; }
    else             { s = e - N_EDGES; d = s; }
}

// ---------------- dtype conversion helpers ----------------
__global__ __launch_bounds__(256) void cvt_bf16_k(const float* __restrict__ in,
                                                  unsigned short* __restrict__ out, int n4) {
    int i = blockIdx.x * 256 + threadIdx.x;
    if (i >= n4) return;
    float4 v = *(const float4*)&in[(size_t)i * 4];
    ushort4 o;
    o.x = f2bf(v.x); o.y = f2bf(v.y); o.z = f2bf(v.z); o.w = f2bf(v.w);
    *(ushort4*)&out[(size_t)i * 4] = o;
}

// Wt[n][k] = bf16(W[k][n])   (256x256)
__global__ __launch_bounds__(256) void cvtT_w_k(const float* __restrict__ W,
                                                unsigned short* __restrict__ Wt) {
    int idx = blockIdx.x * 256 + threadIdx.x;
    int n = idx >> 8, k = idx & 255;
    Wt[idx] = f2bf(W[k * 256 + n]);
}

// ---------------- bf16 MFMA GEMM: C[M,256] = A[M,256] @ Bt^T ----------------
// A: [M][256] bf16 row-major. Bt: [256][256] bf16 with Bt[n][k] = B[k][n].
// C: [M][256] bf16. 128x128 tile, 4 waves (2x2), 64x64 per wave, 16x16x32 MFMA.
// LDS tiles [128 rows][64 k] with 16B-chunk XOR swizzle (chunk ^= row&7).
__global__ __launch_bounds__(256) void gemm_bf16(const unsigned short* __restrict__ A,
                                                 const unsigned short* __restrict__ Bt,
                                                 unsigned short* __restrict__ C, int M) {
    __shared__ unsigned short Al[128 * 64];
    __shared__ unsigned short Bl[128 * 64];
    const int tid = threadIdx.x;
    const int lane = tid & 63;
    const int wid = tid >> 6;
    const int wm = wid >> 1, wn = wid & 1;
    const int row0 = blockIdx.x * 128;
    const int col0 = blockIdx.y * 128;
    const int g = lane >> 4, rl = lane & 15;
    const int srow = lane >> 3, schunk = lane & 7;

    f32x4 acc[4][4];
    #pragma unroll
    for (int m = 0; m < 4; ++m)
        #pragma unroll
        for (int n = 0; n < 4; ++n)
            acc[m][n] = (f32x4){0.f, 0.f, 0.f, 0.f};

    for (int kk = 0; kk < 256; kk += 64) {
        #pragma unroll
        for (int j = 0; j < 4; ++j) {
            int row = (wid * 4 + j) * 8 + srow;   // 0..127
            int sc = schunk ^ (row & 7);
            int grow = row0 + row; if (grow >= M) grow = M - 1;
            uint4 av = *(const uint4*)&A[(size_t)grow * 256 + kk + schunk * 8];
            *(uint4*)&Al[row * 64 + sc * 8] = av;
            int bcol = col0 + row;                // 0..255
            uint4 bv = *(const uint4*)&Bt[(size_t)bcol * 256 + kk + schunk * 8];
            *(uint4*)&Bl[row * 64 + sc * 8] = bv;
        }
        __syncthreads();
        #pragma unroll
        for (int ks = 0; ks < 2; ++ks) {
            bf16x8 af[4], bfr[4];
            int chunk = ks * 4 + g;
            #pragma unroll
            for (int m = 0; m < 4; ++m) {
                int row = wm * 64 + m * 16 + rl;
                int sc = chunk ^ (row & 7);
                af[m] = *(const bf16x8*)&Al[row * 64 + sc * 8];
            }
            #pragma unroll
            for (int n = 0; n < 4; ++n) {
                int col = wn * 64 + n * 16 + rl;
                int sc = chunk ^ (col & 7);
                bfr[n] = *(const bf16x8*)&Bl[col * 64 + sc * 8];
            }
            #pragma unroll
            for (int m = 0; m < 4; ++m)
                #pragma unroll
                for (int n = 0; n < 4; ++n)
                    acc[m][n] = __builtin_amdgcn_mfma_f32_16x16x32_bf16(af[m], bfr[n], acc[m][n], 0, 0, 0);
        }
        __syncthreads();
    }
    // epilogue: C/D frag layout col=lane&15, row=(lane>>4)*4+reg
    #pragma unroll
    for (int m = 0; m < 4; ++m) {
        #pragma unroll
        for (int n = 0; n < 4; ++n) {
            int col = col0 + wn * 64 + n * 16 + rl;
            #pragma unroll
            for (int r = 0; r < 4; ++r) {
                int row = row0 + wm * 64 + m * 16 + g * 4 + r;
                if (row < M) C[(size_t)row * 256 + col] = f2bf(acc[m][n][r]);
            }
        }
    }
}

// ------------- per-row dual dot on bf16 h -------------
__global__ __launch_bounds__(256) void row_dots(const unsigned short* __restrict__ h,
                                                const float* __restrict__ av_s,
                                                const float* __restrict__ av_d,
                                                float* __restrict__ es, float* __restrict__ ed) {
    int row = blockIdx.x * 4 + (threadIdx.x >> 6);
    int lane = threadIdx.x & 63;
    if (row >= N_NODES) return;
    ushort4 hv = *(const ushort4*)&h[(size_t)row * HDIM + lane * 4];
    float h0 = bf2f(hv.x), h1 = bf2f(hv.y), h2 = bf2f(hv.z), h3 = bf2f(hv.w);
    float4 s4 = *(const float4*)&av_s[lane * 4];
    float4 d4 = *(const float4*)&av_d[lane * 4];
    float vs = h0 * s4.x + h1 * s4.y + h2 * s4.z + h3 * s4.w;
    float vd = h0 * d4.x + h1 * d4.y + h2 * d4.z + h3 * d4.w;
    #pragma unroll
    for (int off = 32; off; off >>= 1) {
        vs += __shfl_down(vs, off);
        vd += __shfl_down(vd, off);
    }
    if (lane == 0) { es[row] = vs; ed[row] = vd; }
}

// ---------------- CSR build: histogram -> hierarchical scan -> scatter ----------------
__global__ __launch_bounds__(256) void hist_k(const int* __restrict__ ei, int* __restrict__ hist) {
    int e = blockIdx.x * 256 + threadIdx.x;
    if (e >= ETOT) return;
    int s, d; edge_sd(ei, e, s, d);
    atomicAdd(&hist[d], 1);
}

__global__ __launch_bounds__(256) void scan_bsum_k(const int* __restrict__ hist,
                                                   int* __restrict__ bsum) {
    __shared__ int sdata[256];
    int t = threadIdx.x;
    int i = blockIdx.x * 256 + t;
    sdata[t] = (i < N_NODES) ? hist[i] : 0;
    __syncthreads();
    #pragma unroll
    for (int off = 128; off; off >>= 1) {
        if (t < off) sdata[t] += sdata[t + off];
        __syncthreads();
    }
    if (t == 0) bsum[blockIdx.x] = sdata[0];
}

__global__ __launch_bounds__(256) void scan_boff_k(const int* __restrict__ bsum,
                                                   int* __restrict__ boff) {
    __shared__ int sdata[256];
    int t = threadIdx.x;
    int v = (t < SCAN_NB) ? bsum[t] : 0;
    sdata[t] = v;
    __syncthreads();
    #pragma unroll
    for (int off = 1; off < 256; off <<= 1) {
        int add = (t >= off) ? sdata[t - off] : 0;
        __syncthreads();
        sdata[t] += add;
        __syncthreads();
    }
    if (t < SCAN_NB) boff[t] = sdata[t] - v;
}

__global__ __launch_bounds__(256) void scan_final_k(const int* __restrict__ hist,
                                                    const int* __restrict__ boff,
                                                    int* __restrict__ row_ptr,
                                                    int* __restrict__ cursor) {
    __shared__ int sdata[256];
    int t = threadIdx.x;
    int i = blockIdx.x * 256 + t;
    int v = (i < N_NODES) ? hist[i] : 0;
    sdata[t] = v;
    __syncthreads();
    #pragma unroll
    for (int off = 1; off < 256; off <<= 1) {
        int add = (t >= off) ? sdata[t - off] : 0;
        __syncthreads();
        sdata[t] += add;
        __syncthreads();
    }
    int excl = boff[blockIdx.x] + sdata[t] - v;
    if (i <= N_NODES) {
        row_ptr[i] = excl;
        if (i < N_NODES) cursor[i] = excl;
    }
}

__global__ __launch_bounds__(256) void scatter_k(const int* __restrict__ ei,
                                                 int* __restrict__ cursor,
                                                 int* __restrict__ csr_src) {
    int e = blockIdx.x * 256 + threadIdx.x;
    if (e >= ETOT) return;
    int s, d; edge_sd(ei, e, s, d);
    int pos = atomicAdd(&cursor[d], 1);
    csr_src[pos] = s;
}

// ---------------- fused per-dst softmax + bf16 gather aggregation ----------------
__global__ __launch_bounds__(256) void dst_agg(const int* __restrict__ row_ptr,
                                               const int* __restrict__ csr_src,
                                               const float* __restrict__ es,
                                               const float* __restrict__ ed,
                                               const unsigned short* __restrict__ h,
                                               float* __restrict__ outb) {
    int d = blockIdx.x * 4 + (threadIdx.x >> 6);
    int lane = threadIdx.x & 63;
    if (d >= N_NODES) return;
    int start = row_ptr[d], end = row_ptr[d + 1];
    if (start >= end) {
        *(float4*)&outb[(size_t)d * HDIM + lane * 4] = make_float4(0, 0, 0, 0);
        return;
    }
    float edv = ed[d];
    float m = -INFINITY;
    for (int base = start; base < end; base += 64) {
        int idx = base + lane;
        if (idx < end) {
            float v = leaky(es[csr_src[idx]] + edv, ATT_SLOPE);
            m = fmaxf(m, v);
        }
    }
    #pragma unroll
    for (int off = 32; off; off >>= 1) m = fmaxf(m, __shfl_xor(m, off));
    float ssum = 0.f;
    float4 acc = make_float4(0.f, 0.f, 0.f, 0.f);
    for (int base = start; base < end; base += 64) {
        int idx = base + lane;
        int src = 0; float a = 0.f;
        if (idx < end) {
            src = csr_src[idx];
            a = expf(leaky(es[src] + edv, ATT_SLOPE) - m);
        }
        ssum += a;
        int lim = min(64, end - base);
        for (int j = 0; j < lim; ++j) {
            float aj = __shfl(a, j);
            int sj = __shfl(src, j);
            const ushort4 hv = *(const ushort4*)&h[(size_t)sj * HDIM + lane * 4];
            acc.x += aj * bf2f(hv.x); acc.y += aj * bf2f(hv.y);
            acc.z += aj * bf2f(hv.z); acc.w += aj * bf2f(hv.w);
        }
    }
    #pragma unroll
    for (int off = 32; off; off >>= 1) ssum += __shfl_xor(ssum, off);
    float inv = 1.f / ssum;
    float4 o = make_float4(acc.x * inv, acc.y * inv, acc.z * inv, acc.w * inv);
    *(float4*)&outb[(size_t)d * HDIM + lane * 4] = o;
}

// in-place bias + leaky(0.01) + column sum/sumsq accumulation (fp32 buf)
__global__ __launch_bounds__(256) void post_bn_stats(float* __restrict__ buf,
                                                     const float* __restrict__ bias,
                                                     float* __restrict__ csum,
                                                     float* __restrict__ csq) {
    int t = threadIdx.x;
    int rows_per = (N_NODES + gridDim.x - 1) / gridDim.x;
    int r0 = blockIdx.x * rows_per;
    int r1 = min(r0 + rows_per, N_NODES);
    float b = bias[t];
    float sum = 0.f, sq = 0.f;
    for (int r = r0; r < r1; ++r) {
        float v = buf[(size_t)r * HDIM + t] + b;
        v = leaky(v, ACT_SLOPE);
        buf[(size_t)r * HDIM + t] = v;
        sum += v; sq += v * v;
    }
    atomicAdd(&csum[t], sum);
    atomicAdd(&csq[t], sq);
}

__global__ __launch_bounds__(256) void bn_param(const float* __restrict__ csum,
                                                const float* __restrict__ csq,
                                                const float* __restrict__ gamma,
                                                const float* __restrict__ beta,
                                                float* __restrict__ scale,
                                                float* __restrict__ shift) {
    int t = threadIdx.x;
    float mean = csum[t] / (float)N_NODES;
    float var = csq[t] / (float)N_NODES - mean * mean;
    float sc = gamma[t] * rsqrtf(var + BN_EPS);
    scale[t] = sc;
    shift[t] = beta[t] - mean * sc;
}

// read fp32 buf, apply BN affine, write bf16 (conv2 GEMM input)
__global__ __launch_bounds__(256) void bn_apply(const float* __restrict__ buf,
                                                const float* __restrict__ scale,
                                                const float* __restrict__ shift,
                                                unsigned short* __restrict__ outb) {
    size_t i = (size_t)blockIdx.x * 256 + threadIdx.x;
    size_t base = i * 4;
    if (base >= (size_t)N_NODES * HDIM) return;
    int c = (int)(base % HDIM);
    float4 v = *(const float4*)&buf[base];
    float4 sc = *(const float4*)&scale[c];
    float4 sh = *(const float4*)&shift[c];
    ushort4 o;
    o.x = f2bf(v.x * sc.x + sh.x);
    o.y = f2bf(v.y * sc.y + sh.y);
    o.z = f2bf(v.z * sc.z + sh.z);
    o.w = f2bf(v.w * sc.w + sh.w);
    *(ushort4*)&outb[base] = o;
}

// bias + leaky(0.01) + run-length pooled segment add (batch is sorted)
__global__ __launch_bounds__(256) void post_pool(const float* __restrict__ buf,
                                                 const float* __restrict__ bias,
                                                 const int* __restrict__ batch,
                                                 float* __restrict__ gsum,
                                                 float* __restrict__ gcnt) {
    int t = threadIdx.x;
    int rows_per = (N_NODES + gridDim.x - 1) / gridDim.x;
    int r0 = blockIdx.x * rows_per;
    int r1 = min(r0 + rows_per, N_NODES);
    if (r0 >= r1) return;
    float b = bias[t];
    int curb = -1; float acc = 0.f; int cnt = 0;
    for (int r = r0; r < r1; ++r) {
        int bb = batch[r];
        if (bb != curb) {
            if (curb >= 0) {
                atomicAdd(&gsum[(size_t)curb * HDIM + t], acc);
                if (t == 0) atomicAdd(&gcnt[curb], (float)cnt);
            }
            curb = bb; acc = 0.f; cnt = 0;
        }
        float v = leaky(buf[(size_t)r * HDIM + t] + b, ACT_SLOPE);
        acc += v; cnt++;
    }
    if (curb >= 0) {
        atomicAdd(&gsum[(size_t)curb * HDIM + t], acc);
        if (t == 0) atomicAdd(&gcnt[curb], (float)cnt);
    }
}

// per-graph MLP head (fp32)
__global__ __launch_bounds__(256) void mlp_head(const float* __restrict__ gsum,
                                                const float* __restrict__ gcnt,
                                                const float* __restrict__ lw1,
                                                const float* __restrict__ lb1,
                                                const float* __restrict__ lw2,
                                                const float* __restrict__ lb2,
                                                float* __restrict__ out) {
    __shared__ float g[HDIM];
    __shared__ float hid[HDIM];
    int b = blockIdx.x, t = threadIdx.x;
    float cnt = fmaxf(gcnt[b], 1.f);
    g[t] = gsum[(size_t)b * HDIM + t] / cnt;
    __syncthreads();
    float acc = lb1[t];
    for (int k = 0; k < HDIM; ++k) acc += g[k] * lw1[(size_t)k * HDIM + t];
    hid[t] = leaky(acc, ACT_SLOPE);
    __syncthreads();
    if (t < C_OUT) {
        float o = lb2[t];
        for (int k = 0; k < HDIM; ++k) o += hid[k] * lw2[(size_t)k * C_OUT + t];
        out[(size_t)b * C_OUT + t] = o;
    }
}

extern "C" void kernel_launch(void* const* d_in, const int* in_sizes, int n_in,
                              void* d_out, int out_size, void* d_ws, size_t ws_size,
                              hipStream_t stream) {
    const float* x      = (const float*)d_in[0];
    const int*   ei     = (const int*)d_in[1];
    const int*   batch  = (const int*)d_in[2];
    const float* W1     = (const float*)d_in[4];
    const float* a_src1 = (const float*)d_in[5];
    const float* a_dst1 = (const float*)d_in[6];
    const float* b1     = (const float*)d_in[7];
    const float* gamma  = (const float*)d_in[8];
    const float* beta   = (const float*)d_in[9];
    const float* W2     = (const float*)d_in[10];
    const float* a_src2 = (const float*)d_in[11];
    const float* a_dst2 = (const float*)d_in[12];
    const float* b2     = (const float*)d_in[13];
    const float* lw1    = (const float*)d_in[14];
    const float* lb1    = (const float*)d_in[15];
    const float* lw2    = (const float*)d_in[16];
    const float* lb2    = (const float*)d_in[17];
    float* out = (float*)d_out;

    const size_t NH = (size_t)N_NODES * HDIM;
    char* ws = (char*)d_ws;
    float*          bufB    = (float*)ws;          ws += NH * 4;
    unsigned short* xbf     = (unsigned short*)ws; ws += NH * 2;   // also reused as bn output
    unsigned short* hbf     = (unsigned short*)ws; ws += NH * 2;
    unsigned short* Wt1     = (unsigned short*)ws; ws += 65536 * 2;
    unsigned short* Wt2     = (unsigned short*)ws; ws += 65536 * 2;
    float* e_src   = (float*)ws; ws += N_NODES * 4;
    float* e_dst   = (float*)ws; ws += N_NODES * 4;
    float* csum    = (float*)ws; ws += HDIM * 4;
    float* csq     = (float*)ws; ws += HDIM * 4;
    float* scale   = (float*)ws; ws += HDIM * 4;
    float* shift   = (float*)ws; ws += HDIM * 4;
    float* gsum    = (float*)ws; ws += NGRAPH * HDIM * 4;
    float* gcnt    = (float*)ws; ws += NGRAPH * 4;
    int*   hist    = (int*)ws;   ws += N_NODES * 4;
    int*   row_ptr = (int*)ws;   ws += (N_NODES + 1) * 4;
    int*   cursor  = (int*)ws;   ws += N_NODES * 4;
    int*   bsum    = (int*)ws;   ws += SCAN_NB * 4;
    int*   boff    = (int*)ws;   ws += SCAN_NB * 4;
    int*   csr_src = (int*)ws;   ws += (size_t)ETOT * 4;
    unsigned short* bnbf = xbf;  // alias: xbf dead after conv1 GEMM

    const int edge_blocks = (ETOT + 255) / 256;
    const int wave4_blocks = (N_NODES + 3) / 4;
    const int cvt_blocks = (int)((NH / 4 + 255) / 256);
    dim3 ggrid((N_NODES + 127) / 128, 2);

    // ---- CSR build (once; shared by both convs) ----
    hipMemsetAsync(hist, 0, N_NODES * 4, stream);
    hist_k<<<edge_blocks, 256, 0, stream>>>(ei, hist);
    scan_bsum_k<<<SCAN_NB, 256, 0, stream>>>(hist, bsum);
    scan_boff_k<<<1, 256, 0, stream>>>(bsum, boff);
    scan_final_k<<<SCAN_NB, 256, 0, stream>>>(hist, boff, row_ptr, cursor);
    scatter_k<<<edge_blocks, 256, 0, stream>>>(ei, cursor, csr_src);

    // ---- dtype prep ----
    cvt_bf16_k<<<cvt_blocks, 256, 0, stream>>>(x, xbf, (int)(NH / 4));
    cvtT_w_k<<<256, 256, 0, stream>>>(W1, Wt1);
    cvtT_w_k<<<256, 256, 0, stream>>>(W2, Wt2);

    // ---- conv1 ----
    gemm_bf16<<<ggrid, 256, 0, stream>>>(xbf, Wt1, hbf, N_NODES);
    row_dots<<<wave4_blocks, 256, 0, stream>>>(hbf, a_src1, a_dst1, e_src, e_dst);
    dst_agg<<<wave4_blocks, 256, 0, stream>>>(row_ptr, csr_src, e_src, e_dst, hbf, bufB);

    // ---- bias + leaky + BN ----
    hipMemsetAsync(csum, 0, HDIM * 4, stream);
    hipMemsetAsync(csq, 0, HDIM * 4, stream);
    post_bn_stats<<<256, 256, 0, stream>>>(bufB, b1, csum, csq);
    bn_param<<<1, 256, 0, stream>>>(csum, csq, gamma, beta, scale, shift);
    bn_apply<<<cvt_blocks, 256, 0, stream>>>(bufB, scale, shift, bnbf);

    // ---- conv2 ----
    gemm_bf16<<<ggrid, 256, 0, stream>>>(bnbf, Wt2, hbf, N_NODES);
    row_dots<<<wave4_blocks, 256, 0, stream>>>(hbf, a_src2, a_dst2, e_src, e_dst);
    dst_agg<<<wave4_blocks, 256, 0, stream>>>(row_ptr, csr_src, e_src, e_dst, hbf, bufB);

    // ---- bias + leaky + pool ----
    hipMemsetAsync(gsum, 0, (size_t)NGRAPH * HDIM * 4, stream);
    hipMemsetAsync(gcnt, 0, NGRAPH * 4, stream);
    post_pool<<<256, 256, 0, stream>>>(bufB, b2, batch, gsum, gcnt);

    // ---- MLP head ----
    mlp_head<<<NGRAPH, 256, 0, stream>>>(gsum, gcnt, lw1, lb1, lw2, lb2, out);
}

// Round 5
// 435.382 us; speedup vs baseline: 14.1478x; 1.0863x over previous
//
#include <hip/hip_runtime.h>
#include <math.h>

#define N_NODES 50000
#define N_EDGES 800000
#define ETOT    (N_EDGES + N_NODES)
#define FDIM    256
#define HDIM    256
#define NGRAPH  64
#define C_OUT   10
#define BN_EPS  1e-5f
#define ATT_SLOPE 0.2f
#define ACT_SLOPE 0.01f

#define SCAN_NB ((N_NODES + 255) / 256)   // 196

typedef __attribute__((ext_vector_type(8))) short bf16x8;
typedef __attribute__((ext_vector_type(4))) float f32x4;

__device__ __forceinline__ float leaky(float x, float s) { return x >= 0.f ? x : s * x; }

__device__ __forceinline__ float bf2f(unsigned short u) {
    return __uint_as_float((unsigned)u << 16);
}
__device__ __forceinline__ unsigned short f2bf(float f) {
    unsigned u = __float_as_uint(f);
    u += 0x7FFF + ((u >> 16) & 1);   // RNE
    return (unsigned short)(u >> 16);
}

__device__ __forceinline__ void edge_sd(const int* __restrict__ ei, int e, int& s, int& d) {
    if (e < N_EDGES) { s = ei[e]; d = ei[N_EDGES + e]; }
    else             { s = e - N_EDGES; d = s; }
}

// ---------------- dtype conversion helpers ----------------
__global__ __launch_bounds__(256) void cvt_bf16_k(const float* __restrict__ in,
                                                  unsigned short* __restrict__ out, int n4) {
    int i = blockIdx.x * 256 + threadIdx.x;
    if (i >= n4) return;
    float4 v = *(const float4*)&in[(size_t)i * 4];
    ushort4 o;
    o.x = f2bf(v.x); o.y = f2bf(v.y); o.z = f2bf(v.z); o.w = f2bf(v.w);
    *(ushort4*)&out[(size_t)i * 4] = o;
}

// Wt[n][k] = bf16(W[k][n])   (256x256)
__global__ __launch_bounds__(256) void cvtT_w_k(const float* __restrict__ W,
                                                unsigned short* __restrict__ Wt) {
    int idx = blockIdx.x * 256 + threadIdx.x;
    int n = idx >> 8, k = idx & 255;
    Wt[idx] = f2bf(W[k * 256 + n]);
}

// ---------------- bf16 MFMA GEMM: C[M,256] = A[M,256] @ Bt^T ----------------
__global__ __launch_bounds__(256) void gemm_bf16(const unsigned short* __restrict__ A,
                                                 const unsigned short* __restrict__ Bt,
                                                 unsigned short* __restrict__ C, int M) {
    __shared__ unsigned short Al[128 * 64];
    __shared__ unsigned short Bl[128 * 64];
    const int tid = threadIdx.x;
    const int lane = tid & 63;
    const int wid = tid >> 6;
    const int wm = wid >> 1, wn = wid & 1;
    const int row0 = blockIdx.x * 128;
    const int col0 = blockIdx.y * 128;
    const int g = lane >> 4, rl = lane & 15;
    const int srow = lane >> 3, schunk = lane & 7;

    f32x4 acc[4][4];
    #pragma unroll
    for (int m = 0; m < 4; ++m)
        #pragma unroll
        for (int n = 0; n < 4; ++n)
            acc[m][n] = (f32x4){0.f, 0.f, 0.f, 0.f};

    for (int kk = 0; kk < 256; kk += 64) {
        #pragma unroll
        for (int j = 0; j < 4; ++j) {
            int row = (wid * 4 + j) * 8 + srow;   // 0..127
            int sc = schunk ^ (row & 7);
            int grow = row0 + row; if (grow >= M) grow = M - 1;
            uint4 av = *(const uint4*)&A[(size_t)grow * 256 + kk + schunk * 8];
            *(uint4*)&Al[row * 64 + sc * 8] = av;
            int bcol = col0 + row;                // 0..255
            uint4 bv = *(const uint4*)&Bt[(size_t)bcol * 256 + kk + schunk * 8];
            *(uint4*)&Bl[row * 64 + sc * 8] = bv;
        }
        __syncthreads();
        #pragma unroll
        for (int ks = 0; ks < 2; ++ks) {
            bf16x8 af[4], bfr[4];
            int chunk = ks * 4 + g;
            #pragma unroll
            for (int m = 0; m < 4; ++m) {
                int row = wm * 64 + m * 16 + rl;
                int sc = chunk ^ (row & 7);
                af[m] = *(const bf16x8*)&Al[row * 64 + sc * 8];
            }
            #pragma unroll
            for (int n = 0; n < 4; ++n) {
                int col = wn * 64 + n * 16 + rl;
                int sc = chunk ^ (col & 7);
                bfr[n] = *(const bf16x8*)&Bl[col * 64 + sc * 8];
            }
            #pragma unroll
            for (int m = 0; m < 4; ++m)
                #pragma unroll
                for (int n = 0; n < 4; ++n)
                    acc[m][n] = __builtin_amdgcn_mfma_f32_16x16x32_bf16(af[m], bfr[n], acc[m][n], 0, 0, 0);
        }
        __syncthreads();
    }
    #pragma unroll
    for (int m = 0; m < 4; ++m) {
        #pragma unroll
        for (int n = 0; n < 4; ++n) {
            int col = col0 + wn * 64 + n * 16 + rl;
            #pragma unroll
            for (int r = 0; r < 4; ++r) {
                int row = row0 + wm * 64 + m * 16 + g * 4 + r;
                if (row < M) C[(size_t)row * 256 + col] = f2bf(acc[m][n][r]);
            }
        }
    }
}

// ------------- per-row dual dot on bf16 h -------------
__global__ __launch_bounds__(256) void row_dots(const unsigned short* __restrict__ h,
                                                const float* __restrict__ av_s,
                                                const float* __restrict__ av_d,
                                                float* __restrict__ es, float* __restrict__ ed) {
    int row = blockIdx.x * 4 + (threadIdx.x >> 6);
    int lane = threadIdx.x & 63;
    if (row >= N_NODES) return;
    ushort4 hv = *(const ushort4*)&h[(size_t)row * HDIM + lane * 4];
    float h0 = bf2f(hv.x), h1 = bf2f(hv.y), h2 = bf2f(hv.z), h3 = bf2f(hv.w);
    float4 s4 = *(const float4*)&av_s[lane * 4];
    float4 d4 = *(const float4*)&av_d[lane * 4];
    float vs = h0 * s4.x + h1 * s4.y + h2 * s4.z + h3 * s4.w;
    float vd = h0 * d4.x + h1 * d4.y + h2 * d4.z + h3 * d4.w;
    #pragma unroll
    for (int off = 32; off; off >>= 1) {
        vs += __shfl_down(vs, off);
        vd += __shfl_down(vd, off);
    }
    if (lane == 0) { es[row] = vs; ed[row] = vd; }
}

// ---------------- CSR build ----------------
__global__ __launch_bounds__(256) void hist_k(const int* __restrict__ ei, int* __restrict__ hist) {
    int e = blockIdx.x * 256 + threadIdx.x;
    if (e >= ETOT) return;
    int s, d; edge_sd(ei, e, s, d);
    atomicAdd(&hist[d], 1);
}

__global__ __launch_bounds__(256) void scan_bsum_k(const int* __restrict__ hist,
                                                   int* __restrict__ bsum) {
    __shared__ int sdata[256];
    int t = threadIdx.x;
    int i = blockIdx.x * 256 + t;
    sdata[t] = (i < N_NODES) ? hist[i] : 0;
    __syncthreads();
    #pragma unroll
    for (int off = 128; off; off >>= 1) {
        if (t < off) sdata[t] += sdata[t + off];
        __syncthreads();
    }
    if (t == 0) bsum[blockIdx.x] = sdata[0];
}

__global__ __launch_bounds__(256) void scan_boff_k(const int* __restrict__ bsum,
                                                   int* __restrict__ boff) {
    __shared__ int sdata[256];
    int t = threadIdx.x;
    int v = (t < SCAN_NB) ? bsum[t] : 0;
    sdata[t] = v;
    __syncthreads();
    #pragma unroll
    for (int off = 1; off < 256; off <<= 1) {
        int add = (t >= off) ? sdata[t - off] : 0;
        __syncthreads();
        sdata[t] += add;
        __syncthreads();
    }
    if (t < SCAN_NB) boff[t] = sdata[t] - v;
}

__global__ __launch_bounds__(256) void scan_final_k(const int* __restrict__ hist,
                                                    const int* __restrict__ boff,
                                                    int* __restrict__ row_ptr,
                                                    int* __restrict__ cursor) {
    __shared__ int sdata[256];
    int t = threadIdx.x;
    int i = blockIdx.x * 256 + t;
    int v = (i < N_NODES) ? hist[i] : 0;
    sdata[t] = v;
    __syncthreads();
    #pragma unroll
    for (int off = 1; off < 256; off <<= 1) {
        int add = (t >= off) ? sdata[t - off] : 0;
        __syncthreads();
        sdata[t] += add;
        __syncthreads();
    }
    int excl = boff[blockIdx.x] + sdata[t] - v;
    if (i <= N_NODES) {
        row_ptr[i] = excl;
        if (i < N_NODES) cursor[i] = excl;
    }
}

__global__ __launch_bounds__(256) void scatter_k(const int* __restrict__ ei,
                                                 int* __restrict__ cursor,
                                                 int* __restrict__ csr_src) {
    int e = blockIdx.x * 256 + threadIdx.x;
    if (e >= ETOT) return;
    int s, d; edge_sd(ei, e, s, d);
    int pos = atomicAdd(&cursor[d], 1);
    csr_src[pos] = s;
}

// ---------------- fused per-dst softmax + bf16 gather + bias + leaky -> bf16 ----------------
// one wave per destination node; lane covers 4 features.
// broadcast via v_readlane (wave-uniform j -> SGPR alpha & src, saddr gather loads)
__global__ __launch_bounds__(256) void dst_agg(const int* __restrict__ row_ptr,
                                               const int* __restrict__ csr_src,
                                               const float* __restrict__ es,
                                               const float* __restrict__ ed,
                                               const unsigned short* __restrict__ h,
                                               const float* __restrict__ bias,
                                               unsigned short* __restrict__ outb) {
    int d = blockIdx.x * 4 + (threadIdx.x >> 6);
    int lane = threadIdx.x & 63;
    if (d >= N_NODES) return;
    float4 b4 = *(const float4*)&bias[lane * 4];
    int start = row_ptr[d], end = row_ptr[d + 1];
    if (start >= end) {   // impossible (self-loops), safety only
        ushort4 o;
        o.x = f2bf(leaky(b4.x, ACT_SLOPE)); o.y = f2bf(leaky(b4.y, ACT_SLOPE));
        o.z = f2bf(leaky(b4.z, ACT_SLOPE)); o.w = f2bf(leaky(b4.w, ACT_SLOPE));
        *(ushort4*)&outb[(size_t)d * HDIM + lane * 4] = o;
        return;
    }
    float edv = ed[d];
    // pass 1: max
    float m = -INFINITY;
    for (int base = start; base < end; base += 64) {
        int idx = base + lane;
        if (idx < end) {
            float v = leaky(es[csr_src[idx]] + edv, ATT_SLOPE);
            m = fmaxf(m, v);
        }
    }
    #pragma unroll
    for (int off = 32; off; off >>= 1) m = fmaxf(m, __shfl_xor(m, off));
    // pass 2: exp-weights + gather accumulate (4-deep ILP)
    float ssum = 0.f;
    float4 a0 = {0,0,0,0}, a1 = {0,0,0,0}, a2 = {0,0,0,0}, a3 = {0,0,0,0};
    for (int base = start; base < end; base += 64) {
        int idx = base + lane;
        int src = 0; float a = 0.f;
        if (idx < end) {
            src = csr_src[idx];
            a = expf(leaky(es[src] + edv, ATT_SLOPE) - m);
        }
        ssum += a;
        int lim = end - base; if (lim > 64) lim = 64;
        int j = 0;
        for (; j + 3 < lim; j += 4) {
            float w0 = __uint_as_float(__builtin_amdgcn_readlane(__float_as_uint(a), j + 0));
            float w1 = __uint_as_float(__builtin_amdgcn_readlane(__float_as_uint(a), j + 1));
            float w2 = __uint_as_float(__builtin_amdgcn_readlane(__float_as_uint(a), j + 2));
            float w3 = __uint_as_float(__builtin_amdgcn_readlane(__float_as_uint(a), j + 3));
            int s0 = __builtin_amdgcn_readlane(src, j + 0);
            int s1 = __builtin_amdgcn_readlane(src, j + 1);
            int s2 = __builtin_amdgcn_readlane(src, j + 2);
            int s3 = __builtin_amdgcn_readlane(src, j + 3);
            ushort4 v0 = *(const ushort4*)&h[(size_t)s0 * HDIM + lane * 4];
            ushort4 v1 = *(const ushort4*)&h[(size_t)s1 * HDIM + lane * 4];
            ushort4 v2 = *(const ushort4*)&h[(size_t)s2 * HDIM + lane * 4];
            ushort4 v3 = *(const ushort4*)&h[(size_t)s3 * HDIM + lane * 4];
            a0.x += w0 * bf2f(v0.x); a0.y += w0 * bf2f(v0.y); a0.z += w0 * bf2f(v0.z); a0.w += w0 * bf2f(v0.w);
            a1.x += w1 * bf2f(v1.x); a1.y += w1 * bf2f(v1.y); a1.z += w1 * bf2f(v1.z); a1.w += w1 * bf2f(v1.w);
            a2.x += w2 * bf2f(v2.x); a2.y += w2 * bf2f(v2.y); a2.z += w2 * bf2f(v2.z); a2.w += w2 * bf2f(v2.w);
            a3.x += w3 * bf2f(v3.x); a3.y += w3 * bf2f(v3.y); a3.z += w3 * bf2f(v3.z); a3.w += w3 * bf2f(v3.w);
        }
        for (; j < lim; ++j) {
            float w = __uint_as_float(__builtin_amdgcn_readlane(__float_as_uint(a), j));
            int s = __builtin_amdgcn_readlane(src, j);
            ushort4 v = *(const ushort4*)&h[(size_t)s * HDIM + lane * 4];
            a0.x += w * bf2f(v.x); a0.y += w * bf2f(v.y); a0.z += w * bf2f(v.z); a0.w += w * bf2f(v.w);
        }
    }
    #pragma unroll
    for (int off = 32; off; off >>= 1) ssum += __shfl_xor(ssum, off);
    float inv = 1.f / ssum;
    float4 acc;
    acc.x = (a0.x + a1.x) + (a2.x + a3.x);
    acc.y = (a0.y + a1.y) + (a2.y + a3.y);
    acc.z = (a0.z + a1.z) + (a2.z + a3.z);
    acc.w = (a0.w + a1.w) + (a2.w + a3.w);
    ushort4 o;
    o.x = f2bf(leaky(acc.x * inv + b4.x, ACT_SLOPE));
    o.y = f2bf(leaky(acc.y * inv + b4.y, ACT_SLOPE));
    o.z = f2bf(leaky(acc.z * inv + b4.z, ACT_SLOPE));
    o.w = f2bf(leaky(acc.w * inv + b4.w, ACT_SLOPE));
    *(ushort4*)&outb[(size_t)d * HDIM + lane * 4] = o;
}

// column sum/sumsq over bf16 activations (read-only)
__global__ __launch_bounds__(256) void bn_stats_k(const unsigned short* __restrict__ buf,
                                                  float* __restrict__ csum,
                                                  float* __restrict__ csq) {
    int t = threadIdx.x;
    int rows_per = (N_NODES + gridDim.x - 1) / gridDim.x;
    int r0 = blockIdx.x * rows_per;
    int r1 = min(r0 + rows_per, N_NODES);
    float sum = 0.f, sq = 0.f;
    for (int r = r0; r < r1; ++r) {
        float v = bf2f(buf[(size_t)r * HDIM + t]);
        sum += v; sq += v * v;
    }
    atomicAdd(&csum[t], sum);
    atomicAdd(&csq[t], sq);
}

__global__ __launch_bounds__(256) void bn_param(const float* __restrict__ csum,
                                                const float* __restrict__ csq,
                                                const float* __restrict__ gamma,
                                                const float* __restrict__ beta,
                                                float* __restrict__ scale,
                                                float* __restrict__ shift) {
    int t = threadIdx.x;
    float mean = csum[t] / (float)N_NODES;
    float var = csq[t] / (float)N_NODES - mean * mean;
    float sc = gamma[t] * rsqrtf(var + BN_EPS);
    scale[t] = sc;
    shift[t] = beta[t] - mean * sc;
}

// bf16 in, BN affine, bf16 out (conv2 GEMM input)
__global__ __launch_bounds__(256) void bn_apply(const unsigned short* __restrict__ buf,
                                                const float* __restrict__ scale,
                                                const float* __restrict__ shift,
                                                unsigned short* __restrict__ outb) {
    size_t i = (size_t)blockIdx.x * 256 + threadIdx.x;
    size_t base = i * 4;
    if (base >= (size_t)N_NODES * HDIM) return;
    int c = (int)(base % HDIM);
    ushort4 v = *(const ushort4*)&buf[base];
    float4 sc = *(const float4*)&scale[c];
    float4 sh = *(const float4*)&shift[c];
    ushort4 o;
    o.x = f2bf(bf2f(v.x) * sc.x + sh.x);
    o.y = f2bf(bf2f(v.y) * sc.y + sh.y);
    o.z = f2bf(bf2f(v.z) * sc.z + sh.z);
    o.w = f2bf(bf2f(v.w) * sc.w + sh.w);
    *(ushort4*)&outb[base] = o;
}

// run-length pooled segment add over bf16 activations (bias+leaky already applied)
__global__ __launch_bounds__(256) void post_pool(const unsigned short* __restrict__ buf,
                                                 const int* __restrict__ batch,
                                                 float* __restrict__ gsum,
                                                 float* __restrict__ gcnt) {
    int t = threadIdx.x;
    int rows_per = (N_NODES + gridDim.x - 1) / gridDim.x;
    int r0 = blockIdx.x * rows_per;
    int r1 = min(r0 + rows_per, N_NODES);
    if (r0 >= r1) return;
    int curb = -1; float acc = 0.f; int cnt = 0;
    for (int r = r0; r < r1; ++r) {
        int bb = batch[r];
        if (bb != curb) {
            if (curb >= 0) {
                atomicAdd(&gsum[(size_t)curb * HDIM + t], acc);
                if (t == 0) atomicAdd(&gcnt[curb], (float)cnt);
            }
            curb = bb; acc = 0.f; cnt = 0;
        }
        acc += bf2f(buf[(size_t)r * HDIM + t]);
        cnt++;
    }
    if (curb >= 0) {
        atomicAdd(&gsum[(size_t)curb * HDIM + t], acc);
        if (t == 0) atomicAdd(&gcnt[curb], (float)cnt);
    }
}

// per-graph MLP head (fp32)
__global__ __launch_bounds__(256) void mlp_head(const float* __restrict__ gsum,
                                                const float* __restrict__ gcnt,
                                                const float* __restrict__ lw1,
                                                const float* __restrict__ lb1,
                                                const float* __restrict__ lw2,
                                                const float* __restrict__ lb2,
                                                float* __restrict__ out) {
    __shared__ float g[HDIM];
    __shared__ float hid[HDIM];
    int b = blockIdx.x, t = threadIdx.x;
    float cnt = fmaxf(gcnt[b], 1.f);
    g[t] = gsum[(size_t)b * HDIM + t] / cnt;
    __syncthreads();
    float acc = lb1[t];
    for (int k = 0; k < HDIM; ++k) acc += g[k] * lw1[(size_t)k * HDIM + t];
    hid[t] = leaky(acc, ACT_SLOPE);
    __syncthreads();
    if (t < C_OUT) {
        float o = lb2[t];
        for (int k = 0; k < HDIM; ++k) o += hid[k] * lw2[(size_t)k * C_OUT + t];
        out[(size_t)b * C_OUT + t] = o;
    }
}

extern "C" void kernel_launch(void* const* d_in, const int* in_sizes, int n_in,
                              void* d_out, int out_size, void* d_ws, size_t ws_size,
                              hipStream_t stream) {
    const float* x      = (const float*)d_in[0];
    const int*   ei     = (const int*)d_in[1];
    const int*   batch  = (const int*)d_in[2];
    const float* W1     = (const float*)d_in[4];
    const float* a_src1 = (const float*)d_in[5];
    const float* a_dst1 = (const float*)d_in[6];
    const float* b1     = (const float*)d_in[7];
    const float* gamma  = (const float*)d_in[8];
    const float* beta   = (const float*)d_in[9];
    const float* W2     = (const float*)d_in[10];
    const float* a_src2 = (const float*)d_in[11];
    const float* a_dst2 = (const float*)d_in[12];
    const float* b2     = (const float*)d_in[13];
    const float* lw1    = (const float*)d_in[14];
    const float* lb1    = (const float*)d_in[15];
    const float* lw2    = (const float*)d_in[16];
    const float* lb2    = (const float*)d_in[17];
    float* out = (float*)d_out;

    const size_t NH = (size_t)N_NODES * HDIM;
    char* ws = (char*)d_ws;
    unsigned short* xbf     = (unsigned short*)ws; ws += NH * 2;   // reused as bn output
    unsigned short* hbf     = (unsigned short*)ws; ws += NH * 2;
    unsigned short* aggbf   = (unsigned short*)ws; ws += NH * 2;
    unsigned short* Wt1     = (unsigned short*)ws; ws += 65536 * 2;
    unsigned short* Wt2     = (unsigned short*)ws; ws += 65536 * 2;
    float* e_src   = (float*)ws; ws += N_NODES * 4;
    float* e_dst   = (float*)ws; ws += N_NODES * 4;
    float* csum    = (float*)ws; ws += HDIM * 4;
    float* csq     = (float*)ws; ws += HDIM * 4;
    float* scale   = (float*)ws; ws += HDIM * 4;
    float* shift   = (float*)ws; ws += HDIM * 4;
    float* gsum    = (float*)ws; ws += NGRAPH * HDIM * 4;
    float* gcnt    = (float*)ws; ws += NGRAPH * 4;
    int*   hist    = (int*)ws;   ws += N_NODES * 4;
    int*   row_ptr = (int*)ws;   ws += (N_NODES + 1) * 4;
    int*   cursor  = (int*)ws;   ws += N_NODES * 4;
    int*   bsum    = (int*)ws;   ws += SCAN_NB * 4;
    int*   boff    = (int*)ws;   ws += SCAN_NB * 4;
    int*   csr_src = (int*)ws;   ws += (size_t)ETOT * 4;
    unsigned short* bnbf = xbf;  // alias: xbf dead after conv1 GEMM

    const int edge_blocks = (ETOT + 255) / 256;
    const int wave4_blocks = (N_NODES + 3) / 4;
    const int cvt_blocks = (int)((NH / 4 + 255) / 256);
    dim3 ggrid((N_NODES + 127) / 128, 2);

    // ---- CSR build (once; shared by both convs) ----
    hipMemsetAsync(hist, 0, N_NODES * 4, stream);
    hist_k<<<edge_blocks, 256, 0, stream>>>(ei, hist);
    scan_bsum_k<<<SCAN_NB, 256, 0, stream>>>(hist, bsum);
    scan_boff_k<<<1, 256, 0, stream>>>(bsum, boff);
    scan_final_k<<<SCAN_NB, 256, 0, stream>>>(hist, boff, row_ptr, cursor);
    scatter_k<<<edge_blocks, 256, 0, stream>>>(ei, cursor, csr_src);

    // ---- dtype prep ----
    cvt_bf16_k<<<cvt_blocks, 256, 0, stream>>>(x, xbf, (int)(NH / 4));
    cvtT_w_k<<<256, 256, 0, stream>>>(W1, Wt1);
    cvtT_w_k<<<256, 256, 0, stream>>>(W2, Wt2);

    // ---- conv1 ----
    gemm_bf16<<<ggrid, 256, 0, stream>>>(xbf, Wt1, hbf, N_NODES);
    row_dots<<<wave4_blocks, 256, 0, stream>>>(hbf, a_src1, a_dst1, e_src, e_dst);
    dst_agg<<<wave4_blocks, 256, 0, stream>>>(row_ptr, csr_src, e_src, e_dst, hbf, b1, aggbf);

    // ---- BN ----
    hipMemsetAsync(csum, 0, HDIM * 4, stream);
    hipMemsetAsync(csq, 0, HDIM * 4, stream);
    bn_stats_k<<<256, 256, 0, stream>>>(aggbf, csum, csq);
    bn_param<<<1, 256, 0, stream>>>(csum, csq, gamma, beta, scale, shift);
    bn_apply<<<cvt_blocks, 256, 0, stream>>>(aggbf, scale, shift, bnbf);

    // ---- conv2 ----
    gemm_bf16<<<ggrid, 256, 0, stream>>>(bnbf, Wt2, hbf, N_NODES);
    row_dots<<<wave4_blocks, 256, 0, stream>>>(hbf, a_src2, a_dst2, e_src, e_dst);
    dst_agg<<<wave4_blocks, 256, 0, stream>>>(row_ptr, csr_src, e_src, e_dst, hbf, b2, aggbf);

    // ---- pool ----
    hipMemsetAsync(gsum, 0, (size_t)NGRAPH * HDIM * 4, stream);
    hipMemsetAsync(gcnt, 0, NGRAPH * 4, stream);
    post_pool<<<256, 256, 0, stream>>>(aggbf, batch, gsum, gcnt);

    // ---- MLP head ----
    mlp_head<<<NGRAPH, 256, 0, stream>>>(gsum, gcnt, lw1, lb1, lw2, lb2, out);
}

// Round 6
// 427.599 us; speedup vs baseline: 14.4053x; 1.0182x over previous
//
#include <hip/hip_runtime.h>
#include <math.h>

#define N_NODES 50000
#define N_EDGES 800000
#define ETOT    (N_EDGES + N_NODES)
#define FDIM    256
#define HDIM    256
#define NGRAPH  64
#define C_OUT   10
#define BN_EPS  1e-5f
#define ATT_SLOPE 0.2f
#define ACT_SLOPE 0.01f

#define SCAN_NB ((N_NODES + 255) / 256)   // 196
#define CVT_NB  ((N_NODES * HDIM / 4 + 255) / 256)

typedef __attribute__((ext_vector_type(8))) short bf16x8;
typedef __attribute__((ext_vector_type(4))) float f32x4;

__device__ __forceinline__ float leaky(float x, float s) { return x >= 0.f ? x : s * x; }

__device__ __forceinline__ float bf2f(unsigned short u) {
    return __uint_as_float((unsigned)u << 16);
}
__device__ __forceinline__ unsigned short f2bf(float f) {
    unsigned u = __float_as_uint(f);
    u += 0x7FFF + ((u >> 16) & 1);   // RNE
    return (unsigned short)(u >> 16);
}
__device__ __forceinline__ float rlF(float a, int j) {
    return __uint_as_float(__builtin_amdgcn_readlane(__float_as_uint(a), j));
}

__device__ __forceinline__ void edge_sd(const int* __restrict__ ei, int e, int& s, int& d) {
    if (e < N_EDGES) { s = ei[e]; d = ei[N_EDGES + e]; }
    else             { s = e - N_EDGES; d = s; }
}

// ---------------- merged dtype prep: x->bf16, W1^T->bf16, W2^T->bf16 ----------------
__global__ __launch_bounds__(256) void prep_k(const float* __restrict__ x,
                                              const float* __restrict__ W1,
                                              const float* __restrict__ W2,
                                              unsigned short* __restrict__ xbf,
                                              unsigned short* __restrict__ Wt1,
                                              unsigned short* __restrict__ Wt2) {
    int b = blockIdx.x;
    if (b < CVT_NB) {
        int i = b * 256 + threadIdx.x;
        if (i >= N_NODES * HDIM / 4) return;
        float4 v = *(const float4*)&x[(size_t)i * 4];
        ushort4 o;
        o.x = f2bf(v.x); o.y = f2bf(v.y); o.z = f2bf(v.z); o.w = f2bf(v.w);
        *(ushort4*)&xbf[(size_t)i * 4] = o;
    } else if (b < CVT_NB + 512) {
        int wb = b - CVT_NB;
        const float* W = (wb < 256) ? W1 : W2;
        unsigned short* Wt = (wb < 256) ? Wt1 : Wt2;
        int idx = (wb & 255) * 256 + threadIdx.x;
        int n = idx >> 8, k = idx & 255;
        Wt[idx] = f2bf(W[k * 256 + n]);
    }
}

// ---------------- bf16 MFMA GEMM + fused input affine + fused attention dots ----------------
// C[M,256] = A'[M,256] @ Bt^T  where A' = AFFINE ? A*scale[c]+shift[c] : A
// Epilogue also produces es[row] = h_row . avs, ed[row] = h_row . avd via partial atomics.
template<bool AFFINE>
__global__ __launch_bounds__(256) void gemm_bf16(const unsigned short* __restrict__ A,
                                                 const unsigned short* __restrict__ Bt,
                                                 const float* __restrict__ scale,
                                                 const float* __restrict__ shift,
                                                 const float* __restrict__ avs,
                                                 const float* __restrict__ avd,
                                                 float* __restrict__ es,
                                                 float* __restrict__ ed,
                                                 unsigned short* __restrict__ C, int M) {
    __shared__ unsigned short Al[128 * 64];
    __shared__ unsigned short Bl[128 * 64];
    const int tid = threadIdx.x;
    const int lane = tid & 63;
    const int wid = tid >> 6;
    const int wm = wid >> 1, wn = wid & 1;
    const int row0 = blockIdx.x * 128;
    const int col0 = blockIdx.y * 128;
    const int g = lane >> 4, rl = lane & 15;
    const int srow = lane >> 3, schunk = lane & 7;

    f32x4 acc[4][4];
    #pragma unroll
    for (int m = 0; m < 4; ++m)
        #pragma unroll
        for (int n = 0; n < 4; ++n)
            acc[m][n] = (f32x4){0.f, 0.f, 0.f, 0.f};

    for (int kk = 0; kk < 256; kk += 64) {
        #pragma unroll
        for (int j = 0; j < 4; ++j) {
            int row = (wid * 4 + j) * 8 + srow;   // 0..127
            int sc = schunk ^ (row & 7);
            int grow = row0 + row; if (grow >= M) grow = M - 1;
            uint4 av = *(const uint4*)&A[(size_t)grow * 256 + kk + schunk * 8];
            if (AFFINE) {
                unsigned short* p = (unsigned short*)&av;
                int c0 = kk + schunk * 8;
                #pragma unroll
                for (int q = 0; q < 8; ++q)
                    p[q] = f2bf(bf2f(p[q]) * scale[c0 + q] + shift[c0 + q]);
            }
            *(uint4*)&Al[row * 64 + sc * 8] = av;
            int bcol = col0 + row;                // 0..255
            uint4 bv = *(const uint4*)&Bt[(size_t)bcol * 256 + kk + schunk * 8];
            *(uint4*)&Bl[row * 64 + sc * 8] = bv;
        }
        __syncthreads();
        #pragma unroll
        for (int ks = 0; ks < 2; ++ks) {
            bf16x8 af[4], bfr[4];
            int chunk = ks * 4 + g;
            #pragma unroll
            for (int m = 0; m < 4; ++m) {
                int row = wm * 64 + m * 16 + rl;
                int sc = chunk ^ (row & 7);
                af[m] = *(const bf16x8*)&Al[row * 64 + sc * 8];
            }
            #pragma unroll
            for (int n = 0; n < 4; ++n) {
                int col = wn * 64 + n * 16 + rl;
                int sc = chunk ^ (col & 7);
                bfr[n] = *(const bf16x8*)&Bl[col * 64 + sc * 8];
            }
            #pragma unroll
            for (int m = 0; m < 4; ++m)
                #pragma unroll
                for (int n = 0; n < 4; ++n)
                    acc[m][n] = __builtin_amdgcn_mfma_f32_16x16x32_bf16(af[m], bfr[n], acc[m][n], 0, 0, 0);
        }
        __syncthreads();
    }
    // C write (bf16): C/D frag layout col=lane&15, row=(lane>>4)*4+reg
    #pragma unroll
    for (int m = 0; m < 4; ++m) {
        #pragma unroll
        for (int n = 0; n < 4; ++n) {
            int col = col0 + wn * 64 + n * 16 + rl;
            #pragma unroll
            for (int r = 0; r < 4; ++r) {
                int row = row0 + wm * 64 + m * 16 + g * 4 + r;
                if (row < M) C[(size_t)row * 256 + col] = f2bf(acc[m][n][r]);
            }
        }
    }
    // fused attention dots from fp32 acc: partial over this block's 64 cols
    float as_[4], ad_[4];
    #pragma unroll
    for (int n = 0; n < 4; ++n) {
        int col = col0 + wn * 64 + n * 16 + rl;
        as_[n] = avs[col]; ad_[n] = avd[col];
    }
    #pragma unroll
    for (int m = 0; m < 4; ++m) {
        #pragma unroll
        for (int r = 0; r < 4; ++r) {
            float ps = 0.f, pd = 0.f;
            #pragma unroll
            for (int n = 0; n < 4; ++n) {
                float v = acc[m][n][r];
                ps += v * as_[n]; pd += v * ad_[n];
            }
            #pragma unroll
            for (int off = 1; off < 16; off <<= 1) {
                ps += __shfl_xor(ps, off);
                pd += __shfl_xor(pd, off);
            }
            if (rl == 0) {
                int row = row0 + wm * 64 + m * 16 + g * 4 + r;
                if (row < M) {
                    atomicAdd(&es[row], ps);
                    atomicAdd(&ed[row], pd);
                }
            }
        }
    }
}

// ---------------- CSR build ----------------
__global__ __launch_bounds__(256) void hist_k(const int* __restrict__ ei, int* __restrict__ hist) {
    int e = blockIdx.x * 256 + threadIdx.x;
    if (e >= ETOT) return;
    int s, d; edge_sd(ei, e, s, d);
    atomicAdd(&hist[d], 1);
}

__global__ __launch_bounds__(256) void scan_bsum_k(const int* __restrict__ hist,
                                                   int* __restrict__ bsum) {
    __shared__ int sdata[256];
    int t = threadIdx.x;
    int i = blockIdx.x * 256 + t;
    sdata[t] = (i < N_NODES) ? hist[i] : 0;
    __syncthreads();
    #pragma unroll
    for (int off = 128; off; off >>= 1) {
        if (t < off) sdata[t] += sdata[t + off];
        __syncthreads();
    }
    if (t == 0) bsum[blockIdx.x] = sdata[0];
}

__global__ __launch_bounds__(256) void scan_boff_k(const int* __restrict__ bsum,
                                                   int* __restrict__ boff) {
    __shared__ int sdata[256];
    int t = threadIdx.x;
    int v = (t < SCAN_NB) ? bsum[t] : 0;
    sdata[t] = v;
    __syncthreads();
    #pragma unroll
    for (int off = 1; off < 256; off <<= 1) {
        int add = (t >= off) ? sdata[t - off] : 0;
        __syncthreads();
        sdata[t] += add;
        __syncthreads();
    }
    if (t < SCAN_NB) boff[t] = sdata[t] - v;
}

__global__ __launch_bounds__(256) void scan_final_k(const int* __restrict__ hist,
                                                    const int* __restrict__ boff,
                                                    int* __restrict__ row_ptr,
                                                    int* __restrict__ cursor) {
    __shared__ int sdata[256];
    int t = threadIdx.x;
    int i = blockIdx.x * 256 + t;
    int v = (i < N_NODES) ? hist[i] : 0;
    sdata[t] = v;
    __syncthreads();
    #pragma unroll
    for (int off = 1; off < 256; off <<= 1) {
        int add = (t >= off) ? sdata[t - off] : 0;
        __syncthreads();
        sdata[t] += add;
        __syncthreads();
    }
    int excl = boff[blockIdx.x] + sdata[t] - v;
    if (i <= N_NODES) {
        row_ptr[i] = excl;
        if (i < N_NODES) cursor[i] = excl;
    }
}

__global__ __launch_bounds__(256) void scatter_k(const int* __restrict__ ei,
                                                 int* __restrict__ cursor,
                                                 int* __restrict__ csr_src) {
    int e = blockIdx.x * 256 + threadIdx.x;
    if (e >= ETOT) return;
    int s, d; edge_sd(ei, e, s, d);
    int pos = atomicAdd(&cursor[d], 1);
    csr_src[pos] = s;
}

// ---------------- gather helper: 8-deep ILP, wave-uniform readlane broadcast ----------------
__device__ __forceinline__ void gather8(const unsigned short* __restrict__ hl,
                                        float a, int src, int lim,
                                        float4& A0, float4& A1, float4& A2, float4& A3) {
    int j = 0;
    for (; j + 7 < lim; j += 8) {
        float w0 = rlF(a, j + 0), w1 = rlF(a, j + 1), w2 = rlF(a, j + 2), w3 = rlF(a, j + 3);
        float w4 = rlF(a, j + 4), w5 = rlF(a, j + 5), w6 = rlF(a, j + 6), w7 = rlF(a, j + 7);
        int s0 = __builtin_amdgcn_readlane(src, j + 0);
        int s1 = __builtin_amdgcn_readlane(src, j + 1);
        int s2 = __builtin_amdgcn_readlane(src, j + 2);
        int s3 = __builtin_amdgcn_readlane(src, j + 3);
        int s4 = __builtin_amdgcn_readlane(src, j + 4);
        int s5 = __builtin_amdgcn_readlane(src, j + 5);
        int s6 = __builtin_amdgcn_readlane(src, j + 6);
        int s7 = __builtin_amdgcn_readlane(src, j + 7);
        ushort4 v0 = *(const ushort4*)&hl[(size_t)s0 * HDIM];
        ushort4 v1 = *(const ushort4*)&hl[(size_t)s1 * HDIM];
        ushort4 v2 = *(const ushort4*)&hl[(size_t)s2 * HDIM];
        ushort4 v3 = *(const ushort4*)&hl[(size_t)s3 * HDIM];
        ushort4 v4 = *(const ushort4*)&hl[(size_t)s4 * HDIM];
        ushort4 v5 = *(const ushort4*)&hl[(size_t)s5 * HDIM];
        ushort4 v6 = *(const ushort4*)&hl[(size_t)s6 * HDIM];
        ushort4 v7 = *(const ushort4*)&hl[(size_t)s7 * HDIM];
        A0.x += w0 * bf2f(v0.x); A0.y += w0 * bf2f(v0.y); A0.z += w0 * bf2f(v0.z); A0.w += w0 * bf2f(v0.w);
        A1.x += w1 * bf2f(v1.x); A1.y += w1 * bf2f(v1.y); A1.z += w1 * bf2f(v1.z); A1.w += w1 * bf2f(v1.w);
        A2.x += w2 * bf2f(v2.x); A2.y += w2 * bf2f(v2.y); A2.z += w2 * bf2f(v2.z); A2.w += w2 * bf2f(v2.w);
        A3.x += w3 * bf2f(v3.x); A3.y += w3 * bf2f(v3.y); A3.z += w3 * bf2f(v3.z); A3.w += w3 * bf2f(v3.w);
        A0.x += w4 * bf2f(v4.x); A0.y += w4 * bf2f(v4.y); A0.z += w4 * bf2f(v4.z); A0.w += w4 * bf2f(v4.w);
        A1.x += w5 * bf2f(v5.x); A1.y += w5 * bf2f(v5.y); A1.z += w5 * bf2f(v5.z); A1.w += w5 * bf2f(v5.w);
        A2.x += w6 * bf2f(v6.x); A2.y += w6 * bf2f(v6.y); A2.z += w6 * bf2f(v6.z); A2.w += w6 * bf2f(v6.w);
        A3.x += w7 * bf2f(v7.x); A3.y += w7 * bf2f(v7.y); A3.z += w7 * bf2f(v7.z); A3.w += w7 * bf2f(v7.w);
    }
    for (; j < lim; ++j) {
        float w = rlF(a, j);
        int s = __builtin_amdgcn_readlane(src, j);
        ushort4 v = *(const ushort4*)&hl[(size_t)s * HDIM];
        A0.x += w * bf2f(v.x); A0.y += w * bf2f(v.y); A0.z += w * bf2f(v.z); A0.w += w * bf2f(v.w);
    }
}

// ---------------- fused per-dst softmax + bf16 gather + bias + leaky -> bf16 ----------------
__global__ __launch_bounds__(256) void dst_agg(const int* __restrict__ row_ptr,
                                               const int* __restrict__ csr_src,
                                               const float* __restrict__ es,
                                               const float* __restrict__ ed,
                                               const unsigned short* __restrict__ h,
                                               const float* __restrict__ bias,
                                               unsigned short* __restrict__ outb) {
    int d = blockIdx.x * 4 + (threadIdx.x >> 6);
    int lane = threadIdx.x & 63;
    if (d >= N_NODES) return;
    float4 b4 = *(const float4*)&bias[lane * 4];
    int start = row_ptr[d], end = row_ptr[d + 1];
    int deg = end - start;
    float edv = ed[d];
    const unsigned short* hl = h + lane * 4;
    float4 A0 = {0,0,0,0}, A1 = {0,0,0,0}, A2 = {0,0,0,0}, A3 = {0,0,0,0};
    float ssum = 0.f;

    if (deg > 0 && deg <= 64) {
        // fast path: one pass over es, logits live in registers
        int src = 0; float v = -INFINITY;
        if (lane < deg) {
            src = csr_src[start + lane];
            v = leaky(es[src] + edv, ATT_SLOPE);
        }
        float m = v;
        #pragma unroll
        for (int off = 32; off; off >>= 1) m = fmaxf(m, __shfl_xor(m, off));
        float a = (lane < deg) ? expf(v - m) : 0.f;
        ssum = a;
        gather8(hl, a, src, deg, A0, A1, A2, A3);
    } else if (deg > 64) {
        // rare fallback: two-pass
        float m = -INFINITY;
        for (int base = start; base < end; base += 64) {
            int idx = base + lane;
            if (idx < end) m = fmaxf(m, leaky(es[csr_src[idx]] + edv, ATT_SLOPE));
        }
        #pragma unroll
        for (int off = 32; off; off >>= 1) m = fmaxf(m, __shfl_xor(m, off));
        for (int base = start; base < end; base += 64) {
            int idx = base + lane;
            int src = 0; float a = 0.f;
            if (idx < end) {
                src = csr_src[idx];
                a = expf(leaky(es[src] + edv, ATT_SLOPE) - m);
            }
            ssum += a;
            int lim = end - base; if (lim > 64) lim = 64;
            gather8(hl, a, src, lim, A0, A1, A2, A3);
        }
    } else {
        // deg == 0: impossible (self-loops); emit bias-only
        ssum = 1.f;
    }
    #pragma unroll
    for (int off = 32; off; off >>= 1) ssum += __shfl_xor(ssum, off);
    float inv = (deg > 0) ? (1.f / ssum) : 0.f;
    float4 acc;
    acc.x = (A0.x + A1.x) + (A2.x + A3.x);
    acc.y = (A0.y + A1.y) + (A2.y + A3.y);
    acc.z = (A0.z + A1.z) + (A2.z + A3.z);
    acc.w = (A0.w + A1.w) + (A2.w + A3.w);
    ushort4 o;
    o.x = f2bf(leaky(acc.x * inv + b4.x, ACT_SLOPE));
    o.y = f2bf(leaky(acc.y * inv + b4.y, ACT_SLOPE));
    o.z = f2bf(leaky(acc.z * inv + b4.z, ACT_SLOPE));
    o.w = f2bf(leaky(acc.w * inv + b4.w, ACT_SLOPE));
    *(ushort4*)&outb[(size_t)d * HDIM + lane * 4] = o;
}

// column sum/sumsq over bf16 activations (read-only)
__global__ __launch_bounds__(256) void bn_stats_k(const unsigned short* __restrict__ buf,
                                                  float* __restrict__ csum,
                                                  float* __restrict__ csq) {
    int t = threadIdx.x;
    int rows_per = (N_NODES + gridDim.x - 1) / gridDim.x;
    int r0 = blockIdx.x * rows_per;
    int r1 = min(r0 + rows_per, N_NODES);
    float sum = 0.f, sq = 0.f;
    for (int r = r0; r < r1; ++r) {
        float v = bf2f(buf[(size_t)r * HDIM + t]);
        sum += v; sq += v * v;
    }
    atomicAdd(&csum[t], sum);
    atomicAdd(&csq[t], sq);
}

__global__ __launch_bounds__(256) void bn_param(const float* __restrict__ csum,
                                                const float* __restrict__ csq,
                                                const float* __restrict__ gamma,
                                                const float* __restrict__ beta,
                                                float* __restrict__ scale,
                                                float* __restrict__ shift) {
    int t = threadIdx.x;
    float mean = csum[t] / (float)N_NODES;
    float var = csq[t] / (float)N_NODES - mean * mean;
    float sc = gamma[t] * rsqrtf(var + BN_EPS);
    scale[t] = sc;
    shift[t] = beta[t] - mean * sc;
}

// run-length pooled segment add over bf16 activations (bias+leaky already applied)
__global__ __launch_bounds__(256) void post_pool(const unsigned short* __restrict__ buf,
                                                 const int* __restrict__ batch,
                                                 float* __restrict__ gsum,
                                                 float* __restrict__ gcnt) {
    int t = threadIdx.x;
    int rows_per = (N_NODES + gridDim.x - 1) / gridDim.x;
    int r0 = blockIdx.x * rows_per;
    int r1 = min(r0 + rows_per, N_NODES);
    if (r0 >= r1) return;
    int curb = -1; float acc = 0.f; int cnt = 0;
    for (int r = r0; r < r1; ++r) {
        int bb = batch[r];
        if (bb != curb) {
            if (curb >= 0) {
                atomicAdd(&gsum[(size_t)curb * HDIM + t], acc);
                if (t == 0) atomicAdd(&gcnt[curb], (float)cnt);
            }
            curb = bb; acc = 0.f; cnt = 0;
        }
        acc += bf2f(buf[(size_t)r * HDIM + t]);
        cnt++;
    }
    if (curb >= 0) {
        atomicAdd(&gsum[(size_t)curb * HDIM + t], acc);
        if (t == 0) atomicAdd(&gcnt[curb], (float)cnt);
    }
}

// per-graph MLP head (fp32)
__global__ __launch_bounds__(256) void mlp_head(const float* __restrict__ gsum,
                                                const float* __restrict__ gcnt,
                                                const float* __restrict__ lw1,
                                                const float* __restrict__ lb1,
                                                const float* __restrict__ lw2,
                                                const float* __restrict__ lb2,
                                                float* __restrict__ out) {
    __shared__ float g[HDIM];
    __shared__ float hid[HDIM];
    int b = blockIdx.x, t = threadIdx.x;
    float cnt = fmaxf(gcnt[b], 1.f);
    g[t] = gsum[(size_t)b * HDIM + t] / cnt;
    __syncthreads();
    float acc = lb1[t];
    for (int k = 0; k < HDIM; ++k) acc += g[k] * lw1[(size_t)k * HDIM + t];
    hid[t] = leaky(acc, ACT_SLOPE);
    __syncthreads();
    if (t < C_OUT) {
        float o = lb2[t];
        for (int k = 0; k < HDIM; ++k) o += hid[k] * lw2[(size_t)k * C_OUT + t];
        out[(size_t)b * C_OUT + t] = o;
    }
}

extern "C" void kernel_launch(void* const* d_in, const int* in_sizes, int n_in,
                              void* d_out, int out_size, void* d_ws, size_t ws_size,
                              hipStream_t stream) {
    const float* x      = (const float*)d_in[0];
    const int*   ei     = (const int*)d_in[1];
    const int*   batch  = (const int*)d_in[2];
    const float* W1     = (const float*)d_in[4];
    const float* a_src1 = (const float*)d_in[5];
    const float* a_dst1 = (const float*)d_in[6];
    const float* b1     = (const float*)d_in[7];
    const float* gamma  = (const float*)d_in[8];
    const float* beta   = (const float*)d_in[9];
    const float* W2     = (const float*)d_in[10];
    const float* a_src2 = (const float*)d_in[11];
    const float* a_dst2 = (const float*)d_in[12];
    const float* b2     = (const float*)d_in[13];
    const float* lw1    = (const float*)d_in[14];
    const float* lb1    = (const float*)d_in[15];
    const float* lw2    = (const float*)d_in[16];
    const float* lb2    = (const float*)d_in[17];
    float* out = (float*)d_out;

    const size_t NH = (size_t)N_NODES * HDIM;
    char* ws = (char*)d_ws;
    unsigned short* xbf     = (unsigned short*)ws; ws += NH * 2;
    unsigned short* hbf     = (unsigned short*)ws; ws += NH * 2;
    unsigned short* aggbf   = (unsigned short*)ws; ws += NH * 2;
    unsigned short* Wt1     = (unsigned short*)ws; ws += 65536 * 2;
    unsigned short* Wt2     = (unsigned short*)ws; ws += 65536 * 2;
    float* e_src   = (float*)ws; ws += N_NODES * 4;
    float* e_dst   = (float*)ws; ws += N_NODES * 4;
    float* csum    = (float*)ws; ws += HDIM * 4;
    float* csq     = (float*)ws; ws += HDIM * 4;
    float* scale   = (float*)ws; ws += HDIM * 4;
    float* shift   = (float*)ws; ws += HDIM * 4;
    float* gsum    = (float*)ws; ws += NGRAPH * HDIM * 4;
    float* gcnt    = (float*)ws; ws += NGRAPH * 4;
    int*   hist    = (int*)ws;   ws += N_NODES * 4;
    int*   row_ptr = (int*)ws;   ws += (N_NODES + 1) * 4;
    int*   cursor  = (int*)ws;   ws += N_NODES * 4;
    int*   bsum    = (int*)ws;   ws += SCAN_NB * 4;
    int*   boff    = (int*)ws;   ws += SCAN_NB * 4;
    int*   csr_src = (int*)ws;   ws += (size_t)ETOT * 4;

    const int edge_blocks = (ETOT + 255) / 256;
    const int wave4_blocks = (N_NODES + 3) / 4;
    dim3 ggrid((N_NODES + 127) / 128, 2);

    // ---- CSR build (once; shared by both convs) ----
    hipMemsetAsync(hist, 0, N_NODES * 4, stream);
    hist_k<<<edge_blocks, 256, 0, stream>>>(ei, hist);
    scan_bsum_k<<<SCAN_NB, 256, 0, stream>>>(hist, bsum);
    scan_boff_k<<<1, 256, 0, stream>>>(bsum, boff);
    scan_final_k<<<SCAN_NB, 256, 0, stream>>>(hist, boff, row_ptr, cursor);
    scatter_k<<<edge_blocks, 256, 0, stream>>>(ei, cursor, csr_src);

    // ---- dtype prep (merged) ----
    prep_k<<<CVT_NB + 512, 256, 0, stream>>>(x, W1, W2, xbf, Wt1, Wt2);

    // ---- conv1: GEMM (+dots) -> softmax-gather ----
    hipMemsetAsync(e_src, 0, N_NODES * 4, stream);
    hipMemsetAsync(e_dst, 0, N_NODES * 4, stream);
    gemm_bf16<false><<<ggrid, 256, 0, stream>>>(xbf, Wt1, nullptr, nullptr,
                                                a_src1, a_dst1, e_src, e_dst, hbf, N_NODES);
    dst_agg<<<wave4_blocks, 256, 0, stream>>>(row_ptr, csr_src, e_src, e_dst, hbf, b1, aggbf);

    // ---- BN stats/params ----
    hipMemsetAsync(csum, 0, HDIM * 4, stream);
    hipMemsetAsync(csq, 0, HDIM * 4, stream);
    bn_stats_k<<<256, 256, 0, stream>>>(aggbf, csum, csq);
    bn_param<<<1, 256, 0, stream>>>(csum, csq, gamma, beta, scale, shift);

    // ---- conv2: GEMM (BN affine fused on A-load, +dots) -> softmax-gather ----
    hipMemsetAsync(e_src, 0, N_NODES * 4, stream);
    hipMemsetAsync(e_dst, 0, N_NODES * 4, stream);
    gemm_bf16<true><<<ggrid, 256, 0, stream>>>(aggbf, Wt2, scale, shift,
                                               a_src2, a_dst2, e_src, e_dst, hbf, N_NODES);
    dst_agg<<<wave4_blocks, 256, 0, stream>>>(row_ptr, csr_src, e_src, e_dst, hbf, b2, aggbf);

    // ---- pool ----
    hipMemsetAsync(gsum, 0, (size_t)NGRAPH * HDIM * 4, stream);
    hipMemsetAsync(gcnt, 0, NGRAPH * 4, stream);
    post_pool<<<256, 256, 0, stream>>>(aggbf, batch, gsum, gcnt);

    // ---- MLP head ----
    mlp_head<<<NGRAPH, 256, 0, stream>>>(gsum, gcnt, lw1, lb1, lw2, lb2, out);
}

// Round 7
// 417.803 us; speedup vs baseline: 14.7431x; 1.0234x over previous
//
#include <hip/hip_runtime.h>
#include <math.h>

#define N_NODES 50000
#define N_EDGES 800000
#define ETOT    (N_EDGES + N_NODES)
#define FDIM    256
#define HDIM    256
#define NGRAPH  64
#define C_OUT   10
#define BN_EPS  1e-5f
#define ATT_SLOPE 0.2f
#define ACT_SLOPE 0.01f

#define CVT_NB  ((N_NODES * HDIM / 4 + 255) / 256)
#define NBUCK   ((N_NODES + 15) / 16)    // 3125 buckets of 16 dsts
#define BCAP    512                      // mean load 272, +14 sigma headroom

typedef __attribute__((ext_vector_type(8))) short bf16x8;
typedef __attribute__((ext_vector_type(4))) float f32x4;

__device__ __forceinline__ float leaky(float x, float s) { return x >= 0.f ? x : s * x; }

__device__ __forceinline__ float bf2f(unsigned short u) {
    return __uint_as_float((unsigned)u << 16);
}
__device__ __forceinline__ unsigned short f2bf(float f) {
    unsigned u = __float_as_uint(f);
    u += 0x7FFF + ((u >> 16) & 1);   // RNE
    return (unsigned short)(u >> 16);
}
__device__ __forceinline__ float rlF(float a, int j) {
    return __uint_as_float(__builtin_amdgcn_readlane(__float_as_uint(a), j));
}

__device__ __forceinline__ void edge_sd(const int* __restrict__ ei, int e, int& s, int& d) {
    if (e < N_EDGES) { s = ei[e]; d = ei[N_EDGES + e]; }
    else             { s = e - N_EDGES; d = s; }
}

// ---------------- merged dtype prep: x->bf16, W1^T->bf16, W2^T->bf16 ----------------
__global__ __launch_bounds__(256) void prep_k(const float* __restrict__ x,
                                              const float* __restrict__ W1,
                                              const float* __restrict__ W2,
                                              unsigned short* __restrict__ xbf,
                                              unsigned short* __restrict__ Wt1,
                                              unsigned short* __restrict__ Wt2) {
    int b = blockIdx.x;
    if (b < CVT_NB) {
        int i = b * 256 + threadIdx.x;
        if (i >= N_NODES * HDIM / 4) return;
        float4 v = *(const float4*)&x[(size_t)i * 4];
        ushort4 o;
        o.x = f2bf(v.x); o.y = f2bf(v.y); o.z = f2bf(v.z); o.w = f2bf(v.w);
        *(ushort4*)&xbf[(size_t)i * 4] = o;
    } else if (b < CVT_NB + 512) {
        int wb = b - CVT_NB;
        const float* W = (wb < 256) ? W1 : W2;
        unsigned short* Wt = (wb < 256) ? Wt1 : Wt2;
        int idx = (wb & 255) * 256 + threadIdx.x;
        int n = idx >> 8, k = idx & 255;
        Wt[idx] = f2bf(W[k * 256 + n]);
    }
}

// ---------------- bf16 MFMA GEMM + fused input affine + fused attention dots ----------------
template<bool AFFINE>
__global__ __launch_bounds__(256) void gemm_bf16(const unsigned short* __restrict__ A,
                                                 const unsigned short* __restrict__ Bt,
                                                 const float* __restrict__ scale,
                                                 const float* __restrict__ shift,
                                                 const float* __restrict__ avs,
                                                 const float* __restrict__ avd,
                                                 float* __restrict__ es,
                                                 float* __restrict__ ed,
                                                 unsigned short* __restrict__ C, int M) {
    __shared__ unsigned short Al[128 * 64];
    __shared__ unsigned short Bl[128 * 64];
    const int tid = threadIdx.x;
    const int lane = tid & 63;
    const int wid = tid >> 6;
    const int wm = wid >> 1, wn = wid & 1;
    const int row0 = blockIdx.x * 128;
    const int col0 = blockIdx.y * 128;
    const int g = lane >> 4, rl = lane & 15;
    const int srow = lane >> 3, schunk = lane & 7;

    f32x4 acc[4][4];
    #pragma unroll
    for (int m = 0; m < 4; ++m)
        #pragma unroll
        for (int n = 0; n < 4; ++n)
            acc[m][n] = (f32x4){0.f, 0.f, 0.f, 0.f};

    for (int kk = 0; kk < 256; kk += 64) {
        #pragma unroll
        for (int j = 0; j < 4; ++j) {
            int row = (wid * 4 + j) * 8 + srow;   // 0..127
            int sc = schunk ^ (row & 7);
            int grow = row0 + row; if (grow >= M) grow = M - 1;
            uint4 av = *(const uint4*)&A[(size_t)grow * 256 + kk + schunk * 8];
            if (AFFINE) {
                unsigned short* p = (unsigned short*)&av;
                int c0 = kk + schunk * 8;
                #pragma unroll
                for (int q = 0; q < 8; ++q)
                    p[q] = f2bf(bf2f(p[q]) * scale[c0 + q] + shift[c0 + q]);
            }
            *(uint4*)&Al[row * 64 + sc * 8] = av;
            int bcol = col0 + row;                // 0..255
            uint4 bv = *(const uint4*)&Bt[(size_t)bcol * 256 + kk + schunk * 8];
            *(uint4*)&Bl[row * 64 + sc * 8] = bv;
        }
        __syncthreads();
        #pragma unroll
        for (int ks = 0; ks < 2; ++ks) {
            bf16x8 af[4], bfr[4];
            int chunk = ks * 4 + g;
            #pragma unroll
            for (int m = 0; m < 4; ++m) {
                int row = wm * 64 + m * 16 + rl;
                int sc = chunk ^ (row & 7);
                af[m] = *(const bf16x8*)&Al[row * 64 + sc * 8];
            }
            #pragma unroll
            for (int n = 0; n < 4; ++n) {
                int col = wn * 64 + n * 16 + rl;
                int sc = chunk ^ (col & 7);
                bfr[n] = *(const bf16x8*)&Bl[col * 64 + sc * 8];
            }
            #pragma unroll
            for (int m = 0; m < 4; ++m)
                #pragma unroll
                for (int n = 0; n < 4; ++n)
                    acc[m][n] = __builtin_amdgcn_mfma_f32_16x16x32_bf16(af[m], bfr[n], acc[m][n], 0, 0, 0);
        }
        __syncthreads();
    }
    // C write (bf16): C/D frag layout col=lane&15, row=(lane>>4)*4+reg
    #pragma unroll
    for (int m = 0; m < 4; ++m) {
        #pragma unroll
        for (int n = 0; n < 4; ++n) {
            int col = col0 + wn * 64 + n * 16 + rl;
            #pragma unroll
            for (int r = 0; r < 4; ++r) {
                int row = row0 + wm * 64 + m * 16 + g * 4 + r;
                if (row < M) C[(size_t)row * 256 + col] = f2bf(acc[m][n][r]);
            }
        }
    }
    // fused attention dots from fp32 acc: partial over this block's 64 cols
    float as_[4], ad_[4];
    #pragma unroll
    for (int n = 0; n < 4; ++n) {
        int col = col0 + wn * 64 + n * 16 + rl;
        as_[n] = avs[col]; ad_[n] = avd[col];
    }
    #pragma unroll
    for (int m = 0; m < 4; ++m) {
        #pragma unroll
        for (int r = 0; r < 4; ++r) {
            float ps = 0.f, pd = 0.f;
            #pragma unroll
            for (int n = 0; n < 4; ++n) {
                float v = acc[m][n][r];
                ps += v * as_[n]; pd += v * ad_[n];
            }
            #pragma unroll
            for (int off = 1; off < 16; off <<= 1) {
                ps += __shfl_xor(ps, off);
                pd += __shfl_xor(pd, off);
            }
            if (rl == 0) {
                int row = row0 + wm * 64 + m * 16 + g * 4 + r;
                if (row < M) {
                    atomicAdd(&es[row], ps);
                    atomicAdd(&ed[row], pd);
                }
            }
        }
    }
}

// ---------------- bucketed CSR build ----------------
// bucket b covers dst in [b*16, b*16+16). append packed (src | dlocal<<16).
__global__ __launch_bounds__(256) void append_k(const int* __restrict__ ei,
                                                int* __restrict__ bcur,
                                                int* __restrict__ bstore) {
    int e = blockIdx.x * 256 + threadIdx.x;
    if (e >= ETOT) return;
    int s, d; edge_sd(ei, e, s, d);
    int b = d >> 4;
    int pos = atomicAdd(&bcur[b], 1);
    if (pos < BCAP) bstore[(size_t)b * BCAP + pos] = s | ((d & 15) << 16);
}

// single-block scan of NBUCK bucket sizes -> bucket bases; also writes row_ptr[N]
__global__ __launch_bounds__(256) void scan_buckets(const int* __restrict__ bcnt,
                                                    int* __restrict__ bbase,
                                                    int* __restrict__ row_ptr) {
    __shared__ int s[256];
    constexpr int PER = (NBUCK + 255) / 256;   // 13
    int t = threadIdx.x;
    int loc[PER];
    int sum = 0;
    #pragma unroll
    for (int i = 0; i < PER; ++i) {
        int idx = t * PER + i;
        loc[i] = sum;
        sum += (idx < NBUCK) ? bcnt[idx] : 0;
    }
    s[t] = sum;
    __syncthreads();
    #pragma unroll
    for (int off = 1; off < 256; off <<= 1) {
        int add = (t >= off) ? s[t - off] : 0;
        __syncthreads();
        s[t] += add;
        __syncthreads();
    }
    int base = (t > 0) ? s[t - 1] : 0;
    #pragma unroll
    for (int i = 0; i < PER; ++i) {
        int idx = t * PER + i;
        if (idx < NBUCK) bbase[idx] = base + loc[i];
    }
    if (t == 0) row_ptr[N_NODES] = ETOT;
}

// block per bucket: 16-counter LDS hist+scan, write row_ptr & final CSR placement
__global__ __launch_bounds__(256) void place_k(const int* __restrict__ bcnt,
                                               const int* __restrict__ bbase,
                                               const int* __restrict__ bstore,
                                               int* __restrict__ row_ptr,
                                               int* __restrict__ csr_src) {
    __shared__ int h16[16], e16[16], c16[16];
    int b = blockIdx.x, t = threadIdx.x;
    if (t < 16) { h16[t] = 0; c16[t] = 0; }
    __syncthreads();
    int sz = bcnt[b]; if (sz > BCAP) sz = BCAP;
    int base = bbase[b];
    const int* bs = bstore + (size_t)b * BCAP;
    int v0 = -1, v1 = -1;
    if (t < sz)       { v0 = bs[t];       atomicAdd(&h16[v0 >> 16], 1); }
    if (t + 256 < sz) { v1 = bs[t + 256]; atomicAdd(&h16[v1 >> 16], 1); }
    __syncthreads();
    if (t == 0) {
        int run = 0;
        #pragma unroll
        for (int j = 0; j < 16; ++j) { e16[j] = run; run += h16[j]; }
    }
    __syncthreads();
    if (t < 16) {
        int d = b * 16 + t;
        if (d < N_NODES) row_ptr[d] = base + e16[t];
    }
    if (v0 >= 0) {
        int dl = v0 >> 16;
        int pos = base + e16[dl] + atomicAdd(&c16[dl], 1);
        csr_src[pos] = v0 & 0xFFFF;
    }
    if (v1 >= 0) {
        int dl = v1 >> 16;
        int pos = base + e16[dl] + atomicAdd(&c16[dl], 1);
        csr_src[pos] = v1 & 0xFFFF;
    }
}

// ---------------- gather helper: 4-deep ILP, wave-uniform readlane broadcast ----------------
__device__ __forceinline__ void gather4(const unsigned short* __restrict__ hl,
                                        float a, int src, int lim,
                                        float4& A0, float4& A1, float4& A2, float4& A3) {
    int j = 0;
    for (; j + 3 < lim; j += 4) {
        float w0 = rlF(a, j + 0), w1 = rlF(a, j + 1), w2 = rlF(a, j + 2), w3 = rlF(a, j + 3);
        int s0 = __builtin_amdgcn_readlane(src, j + 0);
        int s1 = __builtin_amdgcn_readlane(src, j + 1);
        int s2 = __builtin_amdgcn_readlane(src, j + 2);
        int s3 = __builtin_amdgcn_readlane(src, j + 3);
        ushort4 v0 = *(const ushort4*)&hl[(size_t)s0 * HDIM];
        ushort4 v1 = *(const ushort4*)&hl[(size_t)s1 * HDIM];
        ushort4 v2 = *(const ushort4*)&hl[(size_t)s2 * HDIM];
        ushort4 v3 = *(const ushort4*)&hl[(size_t)s3 * HDIM];
        A0.x += w0 * bf2f(v0.x); A0.y += w0 * bf2f(v0.y); A0.z += w0 * bf2f(v0.z); A0.w += w0 * bf2f(v0.w);
        A1.x += w1 * bf2f(v1.x); A1.y += w1 * bf2f(v1.y); A1.z += w1 * bf2f(v1.z); A1.w += w1 * bf2f(v1.w);
        A2.x += w2 * bf2f(v2.x); A2.y += w2 * bf2f(v2.y); A2.z += w2 * bf2f(v2.z); A2.w += w2 * bf2f(v2.w);
        A3.x += w3 * bf2f(v3.x); A3.y += w3 * bf2f(v3.y); A3.z += w3 * bf2f(v3.z); A3.w += w3 * bf2f(v3.w);
    }
    for (; j < lim; ++j) {
        float w = rlF(a, j);
        int s = __builtin_amdgcn_readlane(src, j);
        ushort4 v = *(const ushort4*)&hl[(size_t)s * HDIM];
        A0.x += w * bf2f(v.x); A0.y += w * bf2f(v.y); A0.z += w * bf2f(v.z); A0.w += w * bf2f(v.w);
    }
}

// ---------------- fused per-dst softmax + bf16 gather + bias + leaky -> bf16 ----------------
__global__ __launch_bounds__(256) void dst_agg(const int* __restrict__ row_ptr,
                                               const int* __restrict__ csr_src,
                                               const float* __restrict__ es,
                                               const float* __restrict__ ed,
                                               const unsigned short* __restrict__ h,
                                               const float* __restrict__ bias,
                                               unsigned short* __restrict__ outb) {
    int d = blockIdx.x * 4 + (threadIdx.x >> 6);
    int lane = threadIdx.x & 63;
    if (d >= N_NODES) return;
    float4 b4 = *(const float4*)&bias[lane * 4];
    int start = row_ptr[d], end = row_ptr[d + 1];
    int deg = end - start;
    float edv = ed[d];
    const unsigned short* hl = h + lane * 4;
    float4 A0 = {0,0,0,0}, A1 = {0,0,0,0}, A2 = {0,0,0,0}, A3 = {0,0,0,0};
    float ssum = 0.f;

    if (deg > 0 && deg <= 64) {
        // fast path: single pass, logits in registers
        int src = 0; float v = -INFINITY;
        if (lane < deg) {
            src = csr_src[start + lane];
            v = leaky(es[src] + edv, ATT_SLOPE);
        }
        float m = v;
        #pragma unroll
        for (int off = 32; off; off >>= 1) m = fmaxf(m, __shfl_xor(m, off));
        float a = (lane < deg) ? expf(v - m) : 0.f;
        ssum = a;
        gather4(hl, a, src, deg, A0, A1, A2, A3);
    } else if (deg > 64) {
        // rare fallback: two-pass
        float m = -INFINITY;
        for (int base = start; base < end; base += 64) {
            int idx = base + lane;
            if (idx < end) m = fmaxf(m, leaky(es[csr_src[idx]] + edv, ATT_SLOPE));
        }
        #pragma unroll
        for (int off = 32; off; off >>= 1) m = fmaxf(m, __shfl_xor(m, off));
        for (int base = start; base < end; base += 64) {
            int idx = base + lane;
            int src = 0; float a = 0.f;
            if (idx < end) {
                src = csr_src[idx];
                a = expf(leaky(es[src] + edv, ATT_SLOPE) - m);
            }
            ssum += a;
            int lim = end - base; if (lim > 64) lim = 64;
            gather4(hl, a, src, lim, A0, A1, A2, A3);
        }
    } else {
        ssum = 1.f;
    }
    #pragma unroll
    for (int off = 32; off; off >>= 1) ssum += __shfl_xor(ssum, off);
    float inv = (deg > 0) ? (1.f / ssum) : 0.f;
    float4 acc;
    acc.x = (A0.x + A1.x) + (A2.x + A3.x);
    acc.y = (A0.y + A1.y) + (A2.y + A3.y);
    acc.z = (A0.z + A1.z) + (A2.z + A3.z);
    acc.w = (A0.w + A1.w) + (A2.w + A3.w);
    ushort4 o;
    o.x = f2bf(leaky(acc.x * inv + b4.x, ACT_SLOPE));
    o.y = f2bf(leaky(acc.y * inv + b4.y, ACT_SLOPE));
    o.z = f2bf(leaky(acc.z * inv + b4.z, ACT_SLOPE));
    o.w = f2bf(leaky(acc.w * inv + b4.w, ACT_SLOPE));
    *(ushort4*)&outb[(size_t)d * HDIM + lane * 4] = o;
}

// column sum/sumsq over bf16 activations (read-only)
__global__ __launch_bounds__(256) void bn_stats_k(const unsigned short* __restrict__ buf,
                                                  float* __restrict__ csum,
                                                  float* __restrict__ csq) {
    int t = threadIdx.x;
    int rows_per = (N_NODES + gridDim.x - 1) / gridDim.x;
    int r0 = blockIdx.x * rows_per;
    int r1 = min(r0 + rows_per, N_NODES);
    float sum = 0.f, sq = 0.f;
    for (int r = r0; r < r1; ++r) {
        float v = bf2f(buf[(size_t)r * HDIM + t]);
        sum += v; sq += v * v;
    }
    atomicAdd(&csum[t], sum);
    atomicAdd(&csq[t], sq);
}

__global__ __launch_bounds__(256) void bn_param(const float* __restrict__ csum,
                                                const float* __restrict__ csq,
                                                const float* __restrict__ gamma,
                                                const float* __restrict__ beta,
                                                float* __restrict__ scale,
                                                float* __restrict__ shift) {
    int t = threadIdx.x;
    float mean = csum[t] / (float)N_NODES;
    float var = csq[t] / (float)N_NODES - mean * mean;
    float sc = gamma[t] * rsqrtf(var + BN_EPS);
    scale[t] = sc;
    shift[t] = beta[t] - mean * sc;
}

// run-length pooled segment add over bf16 activations (bias+leaky already applied)
__global__ __launch_bounds__(256) void post_pool(const unsigned short* __restrict__ buf,
                                                 const int* __restrict__ batch,
                                                 float* __restrict__ gsum,
                                                 float* __restrict__ gcnt) {
    int t = threadIdx.x;
    int rows_per = (N_NODES + gridDim.x - 1) / gridDim.x;
    int r0 = blockIdx.x * rows_per;
    int r1 = min(r0 + rows_per, N_NODES);
    if (r0 >= r1) return;
    int curb = -1; float acc = 0.f; int cnt = 0;
    for (int r = r0; r < r1; ++r) {
        int bb = batch[r];
        if (bb != curb) {
            if (curb >= 0) {
                atomicAdd(&gsum[(size_t)curb * HDIM + t], acc);
                if (t == 0) atomicAdd(&gcnt[curb], (float)cnt);
            }
            curb = bb; acc = 0.f; cnt = 0;
        }
        acc += bf2f(buf[(size_t)r * HDIM + t]);
        cnt++;
    }
    if (curb >= 0) {
        atomicAdd(&gsum[(size_t)curb * HDIM + t], acc);
        if (t == 0) atomicAdd(&gcnt[curb], (float)cnt);
    }
}

// per-graph MLP head (fp32)
__global__ __launch_bounds__(256) void mlp_head(const float* __restrict__ gsum,
                                                const float* __restrict__ gcnt,
                                                const float* __restrict__ lw1,
                                                const float* __restrict__ lb1,
                                                const float* __restrict__ lw2,
                                                const float* __restrict__ lb2,
                                                float* __restrict__ out) {
    __shared__ float g[HDIM];
    __shared__ float hid[HDIM];
    int b = blockIdx.x, t = threadIdx.x;
    float cnt = fmaxf(gcnt[b], 1.f);
    g[t] = gsum[(size_t)b * HDIM + t] / cnt;
    __syncthreads();
    float acc = lb1[t];
    for (int k = 0; k < HDIM; ++k) acc += g[k] * lw1[(size_t)k * HDIM + t];
    hid[t] = leaky(acc, ACT_SLOPE);
    __syncthreads();
    if (t < C_OUT) {
        float o = lb2[t];
        for (int k = 0; k < HDIM; ++k) o += hid[k] * lw2[(size_t)k * C_OUT + t];
        out[(size_t)b * C_OUT + t] = o;
    }
}

extern "C" void kernel_launch(void* const* d_in, const int* in_sizes, int n_in,
                              void* d_out, int out_size, void* d_ws, size_t ws_size,
                              hipStream_t stream) {
    const float* x      = (const float*)d_in[0];
    const int*   ei     = (const int*)d_in[1];
    const int*   batch  = (const int*)d_in[2];
    const float* W1     = (const float*)d_in[4];
    const float* a_src1 = (const float*)d_in[5];
    const float* a_dst1 = (const float*)d_in[6];
    const float* b1     = (const float*)d_in[7];
    const float* gamma  = (const float*)d_in[8];
    const float* beta   = (const float*)d_in[9];
    const float* W2     = (const float*)d_in[10];
    const float* a_src2 = (const float*)d_in[11];
    const float* a_dst2 = (const float*)d_in[12];
    const float* b2     = (const float*)d_in[13];
    const float* lw1    = (const float*)d_in[14];
    const float* lb1    = (const float*)d_in[15];
    const float* lw2    = (const float*)d_in[16];
    const float* lb2    = (const float*)d_in[17];
    float* out = (float*)d_out;

    const size_t NH = (size_t)N_NODES * HDIM;
    char* ws = (char*)d_ws;
    unsigned short* xbf     = (unsigned short*)ws; ws += NH * 2;
    unsigned short* hbf     = (unsigned short*)ws; ws += NH * 2;
    unsigned short* aggbf   = (unsigned short*)ws; ws += NH * 2;
    unsigned short* Wt1     = (unsigned short*)ws; ws += 65536 * 2;
    unsigned short* Wt2     = (unsigned short*)ws; ws += 65536 * 2;
    float* e_src   = (float*)ws; ws += N_NODES * 4;
    float* e_dst   = (float*)ws; ws += N_NODES * 4;
    float* csum    = (float*)ws; ws += HDIM * 4;
    float* csq     = (float*)ws; ws += HDIM * 4;
    float* scale   = (float*)ws; ws += HDIM * 4;
    float* shift   = (float*)ws; ws += HDIM * 4;
    float* gsum    = (float*)ws; ws += NGRAPH * HDIM * 4;
    float* gcnt    = (float*)ws; ws += NGRAPH * 4;
    int*   row_ptr = (int*)ws;   ws += (N_NODES + 1) * 4;
    int*   bcur    = (int*)ws;   ws += NBUCK * 4;
    int*   bbase   = (int*)ws;   ws += NBUCK * 4;
    int*   csr_src = (int*)ws;   ws += (size_t)ETOT * 4;
    int*   bstore  = (int*)ws;   ws += (size_t)NBUCK * BCAP * 4;

    const int edge_blocks = (ETOT + 255) / 256;
    const int wave4_blocks = (N_NODES + 3) / 4;
    dim3 ggrid((N_NODES + 127) / 128, 2);

    // ---- bucketed CSR build (once; shared by both convs) ----
    hipMemsetAsync(bcur, 0, NBUCK * 4, stream);
    append_k<<<edge_blocks, 256, 0, stream>>>(ei, bcur, bstore);
    scan_buckets<<<1, 256, 0, stream>>>(bcur, bbase, row_ptr);
    place_k<<<NBUCK, 256, 0, stream>>>(bcur, bbase, bstore, row_ptr, csr_src);

    // ---- dtype prep (merged) ----
    prep_k<<<CVT_NB + 512, 256, 0, stream>>>(x, W1, W2, xbf, Wt1, Wt2);

    // ---- conv1: GEMM (+dots) -> softmax-gather ----
    hipMemsetAsync(e_src, 0, (size_t)N_NODES * 8, stream);   // e_src + e_dst (adjacent)
    gemm_bf16<false><<<ggrid, 256, 0, stream>>>(xbf, Wt1, nullptr, nullptr,
                                                a_src1, a_dst1, e_src, e_dst, hbf, N_NODES);
    dst_agg<<<wave4_blocks, 256, 0, stream>>>(row_ptr, csr_src, e_src, e_dst, hbf, b1, aggbf);

    // ---- BN stats/params ----
    hipMemsetAsync(csum, 0, HDIM * 8, stream);               // csum + csq (adjacent)
    bn_stats_k<<<256, 256, 0, stream>>>(aggbf, csum, csq);
    bn_param<<<1, 256, 0, stream>>>(csum, csq, gamma, beta, scale, shift);

    // ---- conv2: GEMM (BN affine fused on A-load, +dots) -> softmax-gather ----
    hipMemsetAsync(e_src, 0, (size_t)N_NODES * 8, stream);
    gemm_bf16<true><<<ggrid, 256, 0, stream>>>(aggbf, Wt2, scale, shift,
                                               a_src2, a_dst2, e_src, e_dst, hbf, N_NODES);
    dst_agg<<<wave4_blocks, 256, 0, stream>>>(row_ptr, csr_src, e_src, e_dst, hbf, b2, aggbf);

    // ---- pool ----
    hipMemsetAsync(gsum, 0, (size_t)(NGRAPH * HDIM + NGRAPH) * 4, stream);  // gsum + gcnt
    post_pool<<<256, 256, 0, stream>>>(aggbf, batch, gsum, gcnt);

    // ---- MLP head ----
    mlp_head<<<NGRAPH, 256, 0, stream>>>(gsum, gcnt, lw1, lb1, lw2, lb2, out);
}

// Round 8
// 366.435 us; speedup vs baseline: 16.8098x; 1.1402x over previous
//
#include <hip/hip_runtime.h>
#include <math.h>

#define N_NODES 50000
#define N_EDGES 800000
#define ETOT    (N_EDGES + N_NODES)
#define FDIM    256
#define HDIM    256
#define NGRAPH  64
#define C_OUT   10
#define BN_EPS  1e-5f
#define ATT_SLOPE 0.2f
#define ACT_SLOPE 0.01f

#define CVT_NB  ((N_NODES * HDIM / 4 + 255) / 256)
#define NBUCK   ((N_NODES + 15) / 16)    // 3125 buckets of 16 dsts
#define BCAP    512                      // bucket capacity (mean 272)
#define SORT_NB 96                       // blocks for count/scatter passes
#define EPB     ((ETOT + SORT_NB - 1) / SORT_NB)

typedef __attribute__((ext_vector_type(8))) short bf16x8;
typedef __attribute__((ext_vector_type(4))) float f32x4;

__device__ __forceinline__ float leaky(float x, float s) { return x >= 0.f ? x : s * x; }

__device__ __forceinline__ float bf2f(unsigned short u) {
    return __uint_as_float((unsigned)u << 16);
}
__device__ __forceinline__ unsigned short f2bf(float f) {
    unsigned u = __float_as_uint(f);
    u += 0x7FFF + ((u >> 16) & 1);   // RNE
    return (unsigned short)(u >> 16);
}
__device__ __forceinline__ float rlF(float a, int j) {
    return __uint_as_float(__builtin_amdgcn_readlane(__float_as_uint(a), j));
}

__device__ __forceinline__ void edge_sd(const int* __restrict__ ei, int e, int& s, int& d) {
    if (e < N_EDGES) { s = ei[e]; d = ei[N_EDGES + e]; }
    else             { s = e - N_EDGES; d = s; }
}

// ---------------- merged dtype prep: x->bf16, W1^T->bf16, W2^T->bf16 ----------------
__global__ __launch_bounds__(256) void prep_k(const float* __restrict__ x,
                                              const float* __restrict__ W1,
                                              const float* __restrict__ W2,
                                              unsigned short* __restrict__ xbf,
                                              unsigned short* __restrict__ Wt1,
                                              unsigned short* __restrict__ Wt2) {
    int b = blockIdx.x;
    if (b < CVT_NB) {
        int i = b * 256 + threadIdx.x;
        if (i >= N_NODES * HDIM / 4) return;
        float4 v = *(const float4*)&x[(size_t)i * 4];
        ushort4 o;
        o.x = f2bf(v.x); o.y = f2bf(v.y); o.z = f2bf(v.z); o.w = f2bf(v.w);
        *(ushort4*)&xbf[(size_t)i * 4] = o;
    } else if (b < CVT_NB + 512) {
        int wb = b - CVT_NB;
        const float* W = (wb < 256) ? W1 : W2;
        unsigned short* Wt = (wb < 256) ? Wt1 : Wt2;
        int idx = (wb & 255) * 256 + threadIdx.x;
        int n = idx >> 8, k = idx & 255;
        Wt[idx] = f2bf(W[k * 256 + n]);
    }
}

// ---------------- bf16 MFMA GEMM + fused input affine + fused attention dots ----------------
template<bool AFFINE>
__global__ __launch_bounds__(256) void gemm_bf16(const unsigned short* __restrict__ A,
                                                 const unsigned short* __restrict__ Bt,
                                                 const float* __restrict__ scale,
                                                 const float* __restrict__ shift,
                                                 const float* __restrict__ avs,
                                                 const float* __restrict__ avd,
                                                 float* __restrict__ es,
                                                 float* __restrict__ ed,
                                                 unsigned short* __restrict__ C, int M) {
    __shared__ unsigned short Al[128 * 64];
    __shared__ unsigned short Bl[128 * 64];
    const int tid = threadIdx.x;
    const int lane = tid & 63;
    const int wid = tid >> 6;
    const int wm = wid >> 1, wn = wid & 1;
    const int row0 = blockIdx.x * 128;
    const int col0 = blockIdx.y * 128;
    const int g = lane >> 4, rl = lane & 15;
    const int srow = lane >> 3, schunk = lane & 7;

    f32x4 acc[4][4];
    #pragma unroll
    for (int m = 0; m < 4; ++m)
        #pragma unroll
        for (int n = 0; n < 4; ++n)
            acc[m][n] = (f32x4){0.f, 0.f, 0.f, 0.f};

    for (int kk = 0; kk < 256; kk += 64) {
        #pragma unroll
        for (int j = 0; j < 4; ++j) {
            int row = (wid * 4 + j) * 8 + srow;   // 0..127
            int sc = schunk ^ (row & 7);
            int grow = row0 + row; if (grow >= M) grow = M - 1;
            uint4 av = *(const uint4*)&A[(size_t)grow * 256 + kk + schunk * 8];
            if (AFFINE) {
                unsigned short* p = (unsigned short*)&av;
                int c0 = kk + schunk * 8;
                #pragma unroll
                for (int q = 0; q < 8; ++q)
                    p[q] = f2bf(bf2f(p[q]) * scale[c0 + q] + shift[c0 + q]);
            }
            *(uint4*)&Al[row * 64 + sc * 8] = av;
            int bcol = col0 + row;                // 0..255
            uint4 bv = *(const uint4*)&Bt[(size_t)bcol * 256 + kk + schunk * 8];
            *(uint4*)&Bl[row * 64 + sc * 8] = bv;
        }
        __syncthreads();
        #pragma unroll
        for (int ks = 0; ks < 2; ++ks) {
            bf16x8 af[4], bfr[4];
            int chunk = ks * 4 + g;
            #pragma unroll
            for (int m = 0; m < 4; ++m) {
                int row = wm * 64 + m * 16 + rl;
                int sc = chunk ^ (row & 7);
                af[m] = *(const bf16x8*)&Al[row * 64 + sc * 8];
            }
            #pragma unroll
            for (int n = 0; n < 4; ++n) {
                int col = wn * 64 + n * 16 + rl;
                int sc = chunk ^ (col & 7);
                bfr[n] = *(const bf16x8*)&Bl[col * 64 + sc * 8];
            }
            #pragma unroll
            for (int m = 0; m < 4; ++m)
                #pragma unroll
                for (int n = 0; n < 4; ++n)
                    acc[m][n] = __builtin_amdgcn_mfma_f32_16x16x32_bf16(af[m], bfr[n], acc[m][n], 0, 0, 0);
        }
        __syncthreads();
    }
    // C write (bf16): C/D frag layout col=lane&15, row=(lane>>4)*4+reg
    #pragma unroll
    for (int m = 0; m < 4; ++m) {
        #pragma unroll
        for (int n = 0; n < 4; ++n) {
            int col = col0 + wn * 64 + n * 16 + rl;
            #pragma unroll
            for (int r = 0; r < 4; ++r) {
                int row = row0 + wm * 64 + m * 16 + g * 4 + r;
                if (row < M) C[(size_t)row * 256 + col] = f2bf(acc[m][n][r]);
            }
        }
    }
    // fused attention dots from fp32 acc: partial over this block's 64 cols
    float as_[4], ad_[4];
    #pragma unroll
    for (int n = 0; n < 4; ++n) {
        int col = col0 + wn * 64 + n * 16 + rl;
        as_[n] = avs[col]; ad_[n] = avd[col];
    }
    #pragma unroll
    for (int m = 0; m < 4; ++m) {
        #pragma unroll
        for (int r = 0; r < 4; ++r) {
            float ps = 0.f, pd = 0.f;
            #pragma unroll
            for (int n = 0; n < 4; ++n) {
                float v = acc[m][n][r];
                ps += v * as_[n]; pd += v * ad_[n];
            }
            #pragma unroll
            for (int off = 1; off < 16; off <<= 1) {
                ps += __shfl_xor(ps, off);
                pd += __shfl_xor(pd, off);
            }
            if (rl == 0) {
                int row = row0 + wm * 64 + m * 16 + g * 4 + r;
                if (row < M) {
                    atomicAdd(&es[row], ps);
                    atomicAdd(&ed[row], pd);
                }
            }
        }
    }
}

// ---------------- atomic-free CSR build (2-pass LDS-histogram bucket sort) ----------------
// pass 1: per-block LDS histogram of buckets -> hist2d[block][bucket] (plain stores)
__global__ __launch_bounds__(256) void count_k(const int* __restrict__ ei,
                                               int* __restrict__ hist2d) {
    __shared__ int lcnt[NBUCK];
    int t = threadIdx.x, blk = blockIdx.x;
    for (int i = t; i < NBUCK; i += 256) lcnt[i] = 0;
    __syncthreads();
    int e0 = blk * EPB, e1 = min(e0 + EPB, ETOT);
    for (int e = e0 + t; e < e1; e += 256) {
        int s, d; edge_sd(ei, e, s, d);
        atomicAdd(&lcnt[d >> 4], 1);      // LDS atomic (cheap)
    }
    __syncthreads();
    int* outp = hist2d + blk * NBUCK;
    for (int i = t; i < NBUCK; i += 256) outp[i] = lcnt[i];
}

// exclusive scan down each bucket column (over SORT_NB blocks), in place; totals -> bcnt
__global__ __launch_bounds__(256) void colscan_k(int* __restrict__ hist2d,
                                                 int* __restrict__ bcnt) {
    int col = blockIdx.x * 256 + threadIdx.x;
    if (col >= NBUCK) return;
    int run = 0;
    for (int b = 0; b < SORT_NB; ++b) {
        int idx = b * NBUCK + col;
        int c = hist2d[idx];
        hist2d[idx] = run;
        run += c;
    }
    bcnt[col] = run;
}

// single-block exclusive scan of NBUCK bucket totals -> bucket csr bases
__global__ __launch_bounds__(256) void scan_buckets(const int* __restrict__ bcnt,
                                                    int* __restrict__ bbase,
                                                    int* __restrict__ row_ptr) {
    __shared__ int s[256];
    constexpr int PER = (NBUCK + 255) / 256;   // 13
    int t = threadIdx.x;
    int loc[PER];
    int sum = 0;
    #pragma unroll
    for (int i = 0; i < PER; ++i) {
        int idx = t * PER + i;
        loc[i] = sum;
        sum += (idx < NBUCK) ? bcnt[idx] : 0;
    }
    s[t] = sum;
    __syncthreads();
    #pragma unroll
    for (int off = 1; off < 256; off <<= 1) {
        int add = (t >= off) ? s[t - off] : 0;
        __syncthreads();
        s[t] += add;
        __syncthreads();
    }
    int base = (t > 0) ? s[t - 1] : 0;
    #pragma unroll
    for (int i = 0; i < PER; ++i) {
        int idx = t * PER + i;
        if (idx < NBUCK) bbase[idx] = base + loc[i];
    }
    if (t == 0) row_ptr[N_NODES] = ETOT;
}

// pass 2: re-read edges; within-bucket rank via LDS atomic; plain store into bstore
__global__ __launch_bounds__(256) void scatter2_k(const int* __restrict__ ei,
                                                  const int* __restrict__ hist2d,
                                                  int* __restrict__ bstore) {
    __shared__ int lcur[NBUCK];
    __shared__ int lbase[NBUCK];
    int t = threadIdx.x, blk = blockIdx.x;
    const int* boff = hist2d + blk * NBUCK;
    for (int i = t; i < NBUCK; i += 256) { lcur[i] = 0; lbase[i] = boff[i]; }
    __syncthreads();
    int e0 = blk * EPB, e1 = min(e0 + EPB, ETOT);
    for (int e = e0 + t; e < e1; e += 256) {
        int s, d; edge_sd(ei, e, s, d);
        int b = d >> 4;
        int r = atomicAdd(&lcur[b], 1);
        int pos = lbase[b] + r;
        if (pos < BCAP) bstore[(size_t)b * BCAP + pos] = s | ((d & 15) << 16);
    }
}

// block per bucket: 16-counter LDS hist+scan, write row_ptr & final CSR placement
__global__ __launch_bounds__(256) void place_k(const int* __restrict__ bcnt,
                                               const int* __restrict__ bbase,
                                               const int* __restrict__ bstore,
                                               int* __restrict__ row_ptr,
                                               int* __restrict__ csr_src) {
    __shared__ int h16[16], e16[16], c16[16];
    int b = blockIdx.x, t = threadIdx.x;
    if (t < 16) { h16[t] = 0; c16[t] = 0; }
    __syncthreads();
    int sz = bcnt[b]; if (sz > BCAP) sz = BCAP;
    int base = bbase[b];
    const int* bs = bstore + (size_t)b * BCAP;
    int v0 = -1, v1 = -1;
    if (t < sz)       { v0 = bs[t];       atomicAdd(&h16[v0 >> 16], 1); }
    if (t + 256 < sz) { v1 = bs[t + 256]; atomicAdd(&h16[v1 >> 16], 1); }
    __syncthreads();
    if (t == 0) {
        int run = 0;
        #pragma unroll
        for (int j = 0; j < 16; ++j) { e16[j] = run; run += h16[j]; }
    }
    __syncthreads();
    if (t < 16) {
        int d = b * 16 + t;
        if (d < N_NODES) row_ptr[d] = base + e16[t];
    }
    if (v0 >= 0) {
        int dl = v0 >> 16;
        int pos = base + e16[dl] + atomicAdd(&c16[dl], 1);
        csr_src[pos] = v0 & 0xFFFF;
    }
    if (v1 >= 0) {
        int dl = v1 >> 16;
        int pos = base + e16[dl] + atomicAdd(&c16[dl], 1);
        csr_src[pos] = v1 & 0xFFFF;
    }
}

// ---------------- gather helper: 4-deep ILP, wave-uniform readlane broadcast ----------------
__device__ __forceinline__ void gather4(const unsigned short* __restrict__ hl,
                                        float a, int src, int lim,
                                        float4& A0, float4& A1, float4& A2, float4& A3) {
    int j = 0;
    for (; j + 3 < lim; j += 4) {
        float w0 = rlF(a, j + 0), w1 = rlF(a, j + 1), w2 = rlF(a, j + 2), w3 = rlF(a, j + 3);
        int s0 = __builtin_amdgcn_readlane(src, j + 0);
        int s1 = __builtin_amdgcn_readlane(src, j + 1);
        int s2 = __builtin_amdgcn_readlane(src, j + 2);
        int s3 = __builtin_amdgcn_readlane(src, j + 3);
        ushort4 v0 = *(const ushort4*)&hl[(size_t)s0 * HDIM];
        ushort4 v1 = *(const ushort4*)&hl[(size_t)s1 * HDIM];
        ushort4 v2 = *(const ushort4*)&hl[(size_t)s2 * HDIM];
        ushort4 v3 = *(const ushort4*)&hl[(size_t)s3 * HDIM];
        A0.x += w0 * bf2f(v0.x); A0.y += w0 * bf2f(v0.y); A0.z += w0 * bf2f(v0.z); A0.w += w0 * bf2f(v0.w);
        A1.x += w1 * bf2f(v1.x); A1.y += w1 * bf2f(v1.y); A1.z += w1 * bf2f(v1.z); A1.w += w1 * bf2f(v1.w);
        A2.x += w2 * bf2f(v2.x); A2.y += w2 * bf2f(v2.y); A2.z += w2 * bf2f(v2.z); A2.w += w2 * bf2f(v2.w);
        A3.x += w3 * bf2f(v3.x); A3.y += w3 * bf2f(v3.y); A3.z += w3 * bf2f(v3.z); A3.w += w3 * bf2f(v3.w);
    }
    for (; j < lim; ++j) {
        float w = rlF(a, j);
        int s = __builtin_amdgcn_readlane(src, j);
        ushort4 v = *(const ushort4*)&hl[(size_t)s * HDIM];
        A0.x += w * bf2f(v.x); A0.y += w * bf2f(v.y); A0.z += w * bf2f(v.z); A0.w += w * bf2f(v.w);
    }
}

// ---------------- fused per-dst softmax + bf16 gather + bias + leaky -> bf16 ----------------
__global__ __launch_bounds__(256) void dst_agg(const int* __restrict__ row_ptr,
                                               const int* __restrict__ csr_src,
                                               const float* __restrict__ es,
                                               const float* __restrict__ ed,
                                               const unsigned short* __restrict__ h,
                                               const float* __restrict__ bias,
                                               unsigned short* __restrict__ outb) {
    int d = blockIdx.x * 4 + (threadIdx.x >> 6);
    int lane = threadIdx.x & 63;
    if (d >= N_NODES) return;
    float4 b4 = *(const float4*)&bias[lane * 4];
    int start = row_ptr[d], end = row_ptr[d + 1];
    int deg = end - start;
    float edv = ed[d];
    const unsigned short* hl = h + lane * 4;
    float4 A0 = {0,0,0,0}, A1 = {0,0,0,0}, A2 = {0,0,0,0}, A3 = {0,0,0,0};
    float ssum = 0.f;

    if (deg > 0 && deg <= 64) {
        // fast path: single pass, logits in registers
        int src = 0; float v = -INFINITY;
        if (lane < deg) {
            src = csr_src[start + lane];
            v = leaky(es[src] + edv, ATT_SLOPE);
        }
        float m = v;
        #pragma unroll
        for (int off = 32; off; off >>= 1) m = fmaxf(m, __shfl_xor(m, off));
        float a = (lane < deg) ? expf(v - m) : 0.f;
        ssum = a;
        gather4(hl, a, src, deg, A0, A1, A2, A3);
    } else if (deg > 64) {
        // rare fallback: two-pass
        float m = -INFINITY;
        for (int base = start; base < end; base += 64) {
            int idx = base + lane;
            if (idx < end) m = fmaxf(m, leaky(es[csr_src[idx]] + edv, ATT_SLOPE));
        }
        #pragma unroll
        for (int off = 32; off; off >>= 1) m = fmaxf(m, __shfl_xor(m, off));
        for (int base = start; base < end; base += 64) {
            int idx = base + lane;
            int src = 0; float a = 0.f;
            if (idx < end) {
                src = csr_src[idx];
                a = expf(leaky(es[src] + edv, ATT_SLOPE) - m);
            }
            ssum += a;
            int lim = end - base; if (lim > 64) lim = 64;
            gather4(hl, a, src, lim, A0, A1, A2, A3);
        }
    } else {
        ssum = 1.f;
    }
    #pragma unroll
    for (int off = 32; off; off >>= 1) ssum += __shfl_xor(ssum, off);
    float inv = (deg > 0) ? (1.f / ssum) : 0.f;
    float4 acc;
    acc.x = (A0.x + A1.x) + (A2.x + A3.x);
    acc.y = (A0.y + A1.y) + (A2.y + A3.y);
    acc.z = (A0.z + A1.z) + (A2.z + A3.z);
    acc.w = (A0.w + A1.w) + (A2.w + A3.w);
    ushort4 o;
    o.x = f2bf(leaky(acc.x * inv + b4.x, ACT_SLOPE));
    o.y = f2bf(leaky(acc.y * inv + b4.y, ACT_SLOPE));
    o.z = f2bf(leaky(acc.z * inv + b4.z, ACT_SLOPE));
    o.w = f2bf(leaky(acc.w * inv + b4.w, ACT_SLOPE));
    *(ushort4*)&outb[(size_t)d * HDIM + lane * 4] = o;
}

// column sum/sumsq over bf16 activations (read-only)
__global__ __launch_bounds__(256) void bn_stats_k(const unsigned short* __restrict__ buf,
                                                  float* __restrict__ csum,
                                                  float* __restrict__ csq) {
    int t = threadIdx.x;
    int rows_per = (N_NODES + gridDim.x - 1) / gridDim.x;
    int r0 = blockIdx.x * rows_per;
    int r1 = min(r0 + rows_per, N_NODES);
    float sum = 0.f, sq = 0.f;
    for (int r = r0; r < r1; ++r) {
        float v = bf2f(buf[(size_t)r * HDIM + t]);
        sum += v; sq += v * v;
    }
    atomicAdd(&csum[t], sum);
    atomicAdd(&csq[t], sq);
}

__global__ __launch_bounds__(256) void bn_param(const float* __restrict__ csum,
                                                const float* __restrict__ csq,
                                                const float* __restrict__ gamma,
                                                const float* __restrict__ beta,
                                                float* __restrict__ scale,
                                                float* __restrict__ shift) {
    int t = threadIdx.x;
    float mean = csum[t] / (float)N_NODES;
    float var = csq[t] / (float)N_NODES - mean * mean;
    float sc = gamma[t] * rsqrtf(var + BN_EPS);
    scale[t] = sc;
    shift[t] = beta[t] - mean * sc;
}

// run-length pooled segment add over bf16 activations (bias+leaky already applied)
__global__ __launch_bounds__(256) void post_pool(const unsigned short* __restrict__ buf,
                                                 const int* __restrict__ batch,
                                                 float* __restrict__ gsum,
                                                 float* __restrict__ gcnt) {
    int t = threadIdx.x;
    int rows_per = (N_NODES + gridDim.x - 1) / gridDim.x;
    int r0 = blockIdx.x * rows_per;
    int r1 = min(r0 + rows_per, N_NODES);
    if (r0 >= r1) return;
    int curb = -1; float acc = 0.f; int cnt = 0;
    for (int r = r0; r < r1; ++r) {
        int bb = batch[r];
        if (bb != curb) {
            if (curb >= 0) {
                atomicAdd(&gsum[(size_t)curb * HDIM + t], acc);
                if (t == 0) atomicAdd(&gcnt[curb], (float)cnt);
            }
            curb = bb; acc = 0.f; cnt = 0;
        }
        acc += bf2f(buf[(size_t)r * HDIM + t]);
        cnt++;
    }
    if (curb >= 0) {
        atomicAdd(&gsum[(size_t)curb * HDIM + t], acc);
        if (t == 0) atomicAdd(&gcnt[curb], (float)cnt);
    }
}

// per-graph MLP head (fp32)
__global__ __launch_bounds__(256) void mlp_head(const float* __restrict__ gsum,
                                                const float* __restrict__ gcnt,
                                                const float* __restrict__ lw1,
                                                const float* __restrict__ lb1,
                                                const float* __restrict__ lw2,
                                                const float* __restrict__ lb2,
                                                float* __restrict__ out) {
    __shared__ float g[HDIM];
    __shared__ float hid[HDIM];
    int b = blockIdx.x, t = threadIdx.x;
    float cnt = fmaxf(gcnt[b], 1.f);
    g[t] = gsum[(size_t)b * HDIM + t] / cnt;
    __syncthreads();
    float acc = lb1[t];
    for (int k = 0; k < HDIM; ++k) acc += g[k] * lw1[(size_t)k * HDIM + t];
    hid[t] = leaky(acc, ACT_SLOPE);
    __syncthreads();
    if (t < C_OUT) {
        float o = lb2[t];
        for (int k = 0; k < HDIM; ++k) o += hid[k] * lw2[(size_t)k * C_OUT + t];
        out[(size_t)b * C_OUT + t] = o;
    }
}

extern "C" void kernel_launch(void* const* d_in, const int* in_sizes, int n_in,
                              void* d_out, int out_size, void* d_ws, size_t ws_size,
                              hipStream_t stream) {
    const float* x      = (const float*)d_in[0];
    const int*   ei     = (const int*)d_in[1];
    const int*   batch  = (const int*)d_in[2];
    const float* W1     = (const float*)d_in[4];
    const float* a_src1 = (const float*)d_in[5];
    const float* a_dst1 = (const float*)d_in[6];
    const float* b1     = (const float*)d_in[7];
    const float* gamma  = (const float*)d_in[8];
    const float* beta   = (const float*)d_in[9];
    const float* W2     = (const float*)d_in[10];
    const float* a_src2 = (const float*)d_in[11];
    const float* a_dst2 = (const float*)d_in[12];
    const float* b2     = (const float*)d_in[13];
    const float* lw1    = (const float*)d_in[14];
    const float* lb1    = (const float*)d_in[15];
    const float* lw2    = (const float*)d_in[16];
    const float* lb2    = (const float*)d_in[17];
    float* out = (float*)d_out;

    const size_t NH = (size_t)N_NODES * HDIM;
    char* ws = (char*)d_ws;
    unsigned short* xbf     = (unsigned short*)ws; ws += NH * 2;
    unsigned short* hbf     = (unsigned short*)ws; ws += NH * 2;
    unsigned short* aggbf   = (unsigned short*)ws; ws += NH * 2;
    unsigned short* Wt1     = (unsigned short*)ws; ws += 65536 * 2;
    unsigned short* Wt2     = (unsigned short*)ws; ws += 65536 * 2;
    float* e_src   = (float*)ws; ws += N_NODES * 4;
    float* e_dst   = (float*)ws; ws += N_NODES * 4;
    float* csum    = (float*)ws; ws += HDIM * 4;
    float* csq     = (float*)ws; ws += HDIM * 4;
    float* scale   = (float*)ws; ws += HDIM * 4;
    float* shift   = (float*)ws; ws += HDIM * 4;
    float* gsum    = (float*)ws; ws += NGRAPH * HDIM * 4;
    float* gcnt    = (float*)ws; ws += NGRAPH * 4;
    int*   row_ptr = (int*)ws;   ws += (N_NODES + 1) * 4;
    int*   bcnt    = (int*)ws;   ws += NBUCK * 4;
    int*   bbase   = (int*)ws;   ws += NBUCK * 4;
    int*   hist2d  = (int*)ws;   ws += (size_t)SORT_NB * NBUCK * 4;
    int*   csr_src = (int*)ws;   ws += (size_t)ETOT * 4;
    int*   bstore  = (int*)ws;   ws += (size_t)NBUCK * BCAP * 4;

    const int wave4_blocks = (N_NODES + 3) / 4;
    dim3 ggrid((N_NODES + 127) / 128, 2);

    // ---- atomic-free CSR build (once; shared by both convs) ----
    count_k<<<SORT_NB, 256, 0, stream>>>(ei, hist2d);
    colscan_k<<<(NBUCK + 255) / 256, 256, 0, stream>>>(hist2d, bcnt);
    scan_buckets<<<1, 256, 0, stream>>>(bcnt, bbase, row_ptr);
    scatter2_k<<<SORT_NB, 256, 0, stream>>>(ei, hist2d, bstore);
    place_k<<<NBUCK, 256, 0, stream>>>(bcnt, bbase, bstore, row_ptr, csr_src);

    // ---- dtype prep (merged) ----
    prep_k<<<CVT_NB + 512, 256, 0, stream>>>(x, W1, W2, xbf, Wt1, Wt2);

    // ---- conv1: GEMM (+dots) -> softmax-gather ----
    hipMemsetAsync(e_src, 0, (size_t)N_NODES * 8, stream);   // e_src + e_dst (adjacent)
    gemm_bf16<false><<<ggrid, 256, 0, stream>>>(xbf, Wt1, nullptr, nullptr,
                                                a_src1, a_dst1, e_src, e_dst, hbf, N_NODES);
    dst_agg<<<wave4_blocks, 256, 0, stream>>>(row_ptr, csr_src, e_src, e_dst, hbf, b1, aggbf);

    // ---- BN stats/params ----
    hipMemsetAsync(csum, 0, HDIM * 8, stream);               // csum + csq (adjacent)
    bn_stats_k<<<256, 256, 0, stream>>>(aggbf, csum, csq);
    bn_param<<<1, 256, 0, stream>>>(csum, csq, gamma, beta, scale, shift);

    // ---- conv2: GEMM (BN affine fused on A-load, +dots) -> softmax-gather ----
    hipMemsetAsync(e_src, 0, (size_t)N_NODES * 8, stream);
    gemm_bf16<true><<<ggrid, 256, 0, stream>>>(aggbf, Wt2, scale, shift,
                                               a_src2, a_dst2, e_src, e_dst, hbf, N_NODES);
    dst_agg<<<wave4_blocks, 256, 0, stream>>>(row_ptr, csr_src, e_src, e_dst, hbf, b2, aggbf);

    // ---- pool ----
    hipMemsetAsync(gsum, 0, (size_t)(NGRAPH * HDIM + NGRAPH) * 4, stream);  // gsum + gcnt
    post_pool<<<256, 256, 0, stream>>>(aggbf, batch, gsum, gcnt);

    // ---- MLP head ----
    mlp_head<<<NGRAPH, 256, 0, stream>>>(gsum, gcnt, lw1, lb1, lw2, lb2, out);
}